// Round 1
// baseline (471.402 us; speedup 1.0000x reference)
//
#include <hip/hip_runtime.h>
#include <math.h>

#define N_NODES 20000
#define E_EDGES 320000
#define TOT_E   (E_EDGES + N_NODES)
#define DHID    256
#define NHEAD   4

// ---------- wave helpers (wave64) ----------
__device__ __forceinline__ float wave_sum(float v) {
#pragma unroll
  for (int off = 32; off; off >>= 1) v += __shfl_xor(v, off);
  return v;
}
__device__ __forceinline__ float wave_max(float v) {
#pragma unroll
  for (int off = 32; off; off >>= 1) v = fmaxf(v, __shfl_xor(v, off));
  return v;
}

// ---------- CSR build ----------
__global__ void zero_int_kernel(int* __restrict__ p, int n) {
  int i = blockIdx.x * blockDim.x + threadIdx.x;
  if (i < n) p[i] = 0;
}

__global__ void hist_kernel(const int* __restrict__ ei, int* __restrict__ deg) {
  int e = blockIdx.x * blockDim.x + threadIdx.x;
  if (e >= TOT_E) return;
  int dst = (e < E_EDGES) ? ei[E_EDGES + e] : (e - E_EDGES);
  atomicAdd(&deg[dst], 1);
}

__global__ void scan_kernel(const int* __restrict__ deg, int* __restrict__ rowp,
                            int* __restrict__ cur) {
  __shared__ int partial[256];
  __shared__ int offs[256];
  const int t = threadIdx.x;
  const int CH = (N_NODES + 255) / 256;  // 79
  const int s = t * CH;
  const int e = min(s + CH, N_NODES);
  int sum = 0;
  for (int i = s; i < e; ++i) sum += deg[i];
  partial[t] = sum;
  __syncthreads();
  if (t == 0) {
    int run = 0;
    for (int i = 0; i < 256; ++i) { offs[i] = run; run += partial[i]; }
  }
  __syncthreads();
  int run = offs[t];
  for (int i = s; i < e; ++i) {
    rowp[i] = run; cur[i] = run; run += deg[i];
  }
  if (t == 0) rowp[N_NODES] = TOT_E;
}

__global__ void scatter_kernel(const int* __restrict__ ei, int* __restrict__ cur,
                               int* __restrict__ colb) {
  int e = blockIdx.x * blockDim.x + threadIdx.x;
  if (e >= TOT_E) return;
  int src, dst;
  if (e < E_EDGES) { src = ei[e]; dst = ei[E_EDGES + e]; }
  else             { src = dst = e - E_EDGES; }
  int pos = atomicAdd(&cur[dst], 1);
  colb[pos] = src;
}

// ---------- f32 tiled GEMM: C[M,256] = A[M,256] @ B[256,256] ----------
__global__ __launch_bounds__(256)
void gemm_f32_kernel(const float* __restrict__ A, const float* __restrict__ B,
                     float* __restrict__ C, int M) {
  __shared__ float As[16][64];
  __shared__ float Bs[16][64];
  const int tid = threadIdx.x;
  const int tx = tid & 15, ty = tid >> 4;
  const int row0 = blockIdx.y * 64, col0 = blockIdx.x * 64;
  const int am  = tid >> 2;           // 0..63 row of A tile
  const int ak  = (tid & 3) << 2;     // 0,4,8,12 k0 of A tile
  const int bkr = tid >> 4;           // 0..15 k of B tile
  const int bn0 = (tid & 15) << 2;    // 0..60 n0 of B tile
  const int ar = row0 + am;
  const bool arow_ok = (ar < M);
  float acc[4][4] = {{0.f}};
  for (int kk = 0; kk < 256; kk += 16) {
    float4 av = arow_ok ? *reinterpret_cast<const float4*>(&A[ar * 256 + kk + ak])
                        : make_float4(0.f, 0.f, 0.f, 0.f);
    As[ak + 0][am] = av.x; As[ak + 1][am] = av.y;
    As[ak + 2][am] = av.z; As[ak + 3][am] = av.w;
    *reinterpret_cast<float4*>(&Bs[bkr][bn0]) =
        *reinterpret_cast<const float4*>(&B[(kk + bkr) * 256 + col0 + bn0]);
    __syncthreads();
#pragma unroll
    for (int k = 0; k < 16; ++k) {
      float4 a = *reinterpret_cast<const float4*>(&As[k][ty << 2]);
      float4 b = *reinterpret_cast<const float4*>(&Bs[k][tx << 2]);
      acc[0][0] += a.x * b.x; acc[0][1] += a.x * b.y; acc[0][2] += a.x * b.z; acc[0][3] += a.x * b.w;
      acc[1][0] += a.y * b.x; acc[1][1] += a.y * b.y; acc[1][2] += a.y * b.z; acc[1][3] += a.y * b.w;
      acc[2][0] += a.z * b.x; acc[2][1] += a.z * b.y; acc[2][2] += a.z * b.z; acc[2][3] += a.z * b.w;
      acc[3][0] += a.w * b.x; acc[3][1] += a.w * b.y; acc[3][2] += a.w * b.z; acc[3][3] += a.w * b.w;
    }
    __syncthreads();
  }
#pragma unroll
  for (int i = 0; i < 4; ++i) {
    int r = row0 + (ty << 2) + i;
    if (r < M) {
      *reinterpret_cast<float4*>(&C[r * 256 + col0 + (tx << 2)]) =
          make_float4(acc[i][0], acc[i][1], acc[i][2], acc[i][3]);
    }
  }
}

// ---------- per-node attention logits: as[n,h] = h[n,h,:]·a_src[h,:] ----------
__global__ __launch_bounds__(256)
void alpha_kernel(const float* __restrict__ h, const float* __restrict__ a_src,
                  const float* __restrict__ a_dst, float* __restrict__ as_,
                  float* __restrict__ ad_) {
  const int n = blockIdx.x;
  const int t = threadIdx.x;
  const int head = t >> 6, lane = t & 63;
  float v = h[n * 256 + t];
  float ps = wave_sum(v * a_src[t]);
  float pd = wave_sum(v * a_dst[t]);
  if (lane == 0) { as_[n * 4 + head] = ps; ad_[n * 4 + head] = pd; }
}

// ---------- GAT aggregate + bias + LayerNorm (+residual) + ELU ----------
__global__ __launch_bounds__(256)
void aggregate_kernel(const float* __restrict__ h, const float* __restrict__ as_,
                      const float* __restrict__ ad_, const int* __restrict__ rowp,
                      const int* __restrict__ colb, const float* __restrict__ bias,
                      const float* __restrict__ gamma, const float* __restrict__ beta,
                      const float* __restrict__ resid, float* __restrict__ outbuf) {
  const int d = blockIdx.x;
  const int t = threadIdx.x;
  const int head = t >> 6, lane = t & 63;
  const int start = rowp[d];
  const int deg = rowp[d + 1] - start;
  const float ad_d = ad_[d * 4 + head];
  // pass A: per-head max of leaky_relu(as[s]+ad[d])
  float mloc = -INFINITY;
  for (int i = lane; i < deg; i += 64) {
    int s = colb[start + i];
    float e = as_[s * 4 + head] + ad_d;
    e = (e >= 0.f) ? e : 0.2f * e;
    mloc = fmaxf(mloc, e);
  }
  const float m = wave_max(mloc);
  float zloc = 0.f;
  for (int i = lane; i < deg; i += 64) {
    int s = colb[start + i];
    float e = as_[s * 4 + head] + ad_d;
    e = (e >= 0.f) ? e : 0.2f * e;
    zloc += expf(e - m);
  }
  const float z = wave_sum(zloc);
  const float inv = 1.f / (z + 1e-16f);
  // pass B: weighted sum of h[src]
  float acc = 0.f;
  for (int i = 0; i < deg; ++i) {
    int s = colb[start + i];
    float e = as_[s * 4 + head] + ad_d;
    e = (e >= 0.f) ? e : 0.2f * e;
    float w = expf(e - m) * inv;
    acc += w * h[s * 256 + t];
  }
  float val = acc + bias[t];
  // LayerNorm over 256 (block-wide)
  __shared__ float red[8];
  float sv = wave_sum(val);
  float sq = wave_sum(val * val);
  if (lane == 0) { red[head] = sv; red[4 + head] = sq; }
  __syncthreads();
  float tot  = red[0] + red[1] + red[2] + red[3];
  float totq = red[4] + red[5] + red[6] + red[7];
  float mu  = tot * (1.f / 256.f);
  float var = totq * (1.f / 256.f) - mu * mu;
  float y = (val - mu) * rsqrtf(var + 1e-5f) * gamma[t] + beta[t];
  if (resid) y += resid[d * 256 + t];
  outbuf[d * 256 + t] = (y > 0.f) ? y : expm1f(y);
}

// ---------- pooling ----------
__global__ __launch_bounds__(256)
void score_kernel(const float* __restrict__ x2, const float* __restrict__ aw,
                  const float* __restrict__ ab, float* __restrict__ s) {
  int gid = blockIdx.x * blockDim.x + threadIdx.x;
  int n = gid >> 6, lane = gid & 63;
  if (n >= N_NODES) return;
  float4 xv = *reinterpret_cast<const float4*>(&x2[n * 256 + lane * 4]);
  float4 wv = *reinterpret_cast<const float4*>(&aw[lane * 4]);
  float p = xv.x * wv.x + xv.y * wv.y + xv.z * wv.z + xv.w * wv.w;
  p = wave_sum(p);
  if (lane == 0) s[n] = p + ab[0];
}

__global__ __launch_bounds__(256)
void softmax_reduce_kernel(const float* __restrict__ s, float* __restrict__ mz) {
  __shared__ float red[4];
  const int t = threadIdx.x, lane = t & 63, wid = t >> 6;
  float m = -INFINITY;
  for (int n = t; n < N_NODES; n += 256) m = fmaxf(m, s[n]);
  m = wave_max(m);
  if (lane == 0) red[wid] = m;
  __syncthreads();
  m = fmaxf(fmaxf(red[0], red[1]), fmaxf(red[2], red[3]));
  __syncthreads();
  float z = 0.f;
  for (int n = t; n < N_NODES; n += 256) z += expf(s[n] - m);
  z = wave_sum(z);
  if (lane == 0) red[wid] = z;
  __syncthreads();
  if (t == 0) { mz[0] = m; mz[1] = red[0] + red[1] + red[2] + red[3]; }
}

__global__ __launch_bounds__(256)
void pool_partial_kernel(const float* __restrict__ x2, const float* __restrict__ s,
                         const float* __restrict__ mz, float* __restrict__ part) {
  const int t = threadIdx.x, b = blockIdx.x;
  const float m = mz[0];
  const float invz = 1.f / mz[1];
  float acc = 0.f;
  for (int n = b; n < N_NODES; n += 256) {
    float w = expf(s[n] - m);
    acc += w * x2[n * 256 + t];
  }
  part[b * 256 + t] = acc * invz;
}

__global__ __launch_bounds__(256)
void pool_final_kernel(const float* __restrict__ part, float* __restrict__ out) {
  const int t = threadIdx.x;
  float acc = 0.f;
  for (int b = 0; b < 256; ++b) acc += part[b * 256 + t];
  out[t] = acc;
}

extern "C" void kernel_launch(void* const* d_in, const int* in_sizes, int n_in,
                              void* d_out, int out_size, void* d_ws, size_t ws_size,
                              hipStream_t stream) {
  const float* x      = (const float*)d_in[0];
  const int*   ei     = (const int*)d_in[1];
  const float* W1     = (const float*)d_in[2];
  const float* b1     = (const float*)d_in[3];
  const float* a_src1 = (const float*)d_in[4];
  const float* a_dst1 = (const float*)d_in[5];
  const float* W2     = (const float*)d_in[6];
  const float* b2     = (const float*)d_in[7];
  const float* a_src2 = (const float*)d_in[8];
  const float* a_dst2 = (const float*)d_in[9];
  const float* g1     = (const float*)d_in[10];
  const float* be1    = (const float*)d_in[11];
  const float* g2     = (const float*)d_in[12];
  const float* be2    = (const float*)d_in[13];
  const float* attn_w = (const float*)d_in[14];
  const float* attn_b = (const float*)d_in[15];
  float* out = (float*)d_out;

  char* p = (char*)d_ws;
  auto alloc = [&](size_t bytes) {
    char* r = p;
    p += (bytes + 255) & ~size_t(255);
    return r;
  };
  float* h    = (float*)alloc((size_t)N_NODES * 256 * 4);
  float* x1   = (float*)alloc((size_t)N_NODES * 256 * 4);
  float* x2   = (float*)alloc((size_t)N_NODES * 256 * 4);
  float* as_  = (float*)alloc((size_t)N_NODES * 4 * 4);
  float* ad_  = (float*)alloc((size_t)N_NODES * 4 * 4);
  float* sbuf = (float*)alloc((size_t)N_NODES * 4);
  float* mz   = (float*)alloc(256);
  float* part = (float*)alloc((size_t)256 * 256 * 4);
  int* deg    = (int*)alloc((size_t)N_NODES * 4);
  int* rowp   = (int*)alloc((size_t)(N_NODES + 1) * 4);
  int* cur    = (int*)alloc((size_t)N_NODES * 4);
  int* colb   = (int*)alloc((size_t)TOT_E * 4);

  const int EB = (TOT_E + 255) / 256;

  // CSR build (per call; deterministic up to within-bucket order)
  zero_int_kernel<<<(N_NODES + 255) / 256, 256, 0, stream>>>(deg, N_NODES);
  hist_kernel<<<EB, 256, 0, stream>>>(ei, deg);
  scan_kernel<<<1, 256, 0, stream>>>(deg, rowp, cur);
  scatter_kernel<<<EB, 256, 0, stream>>>(ei, cur, colb);

  dim3 ggrid(4, (N_NODES + 63) / 64);

  // layer 1
  gemm_f32_kernel<<<ggrid, 256, 0, stream>>>(x, W1, h, N_NODES);
  alpha_kernel<<<N_NODES, 256, 0, stream>>>(h, a_src1, a_dst1, as_, ad_);
  aggregate_kernel<<<N_NODES, 256, 0, stream>>>(h, as_, ad_, rowp, colb, b1, g1, be1,
                                                nullptr, x1);
  // layer 2
  gemm_f32_kernel<<<ggrid, 256, 0, stream>>>(x1, W2, h, N_NODES);
  alpha_kernel<<<N_NODES, 256, 0, stream>>>(h, a_src2, a_dst2, as_, ad_);
  aggregate_kernel<<<N_NODES, 256, 0, stream>>>(h, as_, ad_, rowp, colb, b2, g2, be2,
                                                x1, x2);
  // pooling
  score_kernel<<<(N_NODES * 64 + 255) / 256, 256, 0, stream>>>(x2, attn_w, attn_b, sbuf);
  softmax_reduce_kernel<<<1, 256, 0, stream>>>(sbuf, mz);
  pool_partial_kernel<<<256, 256, 0, stream>>>(x2, sbuf, mz, part);
  pool_final_kernel<<<1, 256, 0, stream>>>(part, out);
}

// Round 2
// 379.313 us; speedup vs baseline: 1.2428x; 1.2428x over previous
//
#include <hip/hip_runtime.h>
#include <math.h>

#define N_NODES 20000
#define E_EDGES 320000
#define TOT_E   (E_EDGES + N_NODES)
#define DHID    256
#define NHEAD   4
#define CHUNK   256   // edges staged in LDS per online-softmax chunk

// ---------- wave helpers (wave64) ----------
__device__ __forceinline__ float wave_sum(float v) {
#pragma unroll
  for (int off = 32; off; off >>= 1) v += __shfl_xor(v, off);
  return v;
}
__device__ __forceinline__ float wave_max(float v) {
#pragma unroll
  for (int off = 32; off; off >>= 1) v = fmaxf(v, __shfl_xor(v, off));
  return v;
}

// ---------- CSR build ----------
__global__ void zero_int_kernel(int* __restrict__ p, int n) {
  int i = blockIdx.x * blockDim.x + threadIdx.x;
  if (i < n) p[i] = 0;
}

__global__ void hist_kernel(const int* __restrict__ ei, int* __restrict__ deg) {
  int e = blockIdx.x * blockDim.x + threadIdx.x;
  if (e >= TOT_E) return;
  int dst = (e < E_EDGES) ? ei[E_EDGES + e] : (e - E_EDGES);
  atomicAdd(&deg[dst], 1);
}

__global__ void scan_kernel(const int* __restrict__ deg, int* __restrict__ rowp,
                            int* __restrict__ cur) {
  __shared__ int partial[256];
  __shared__ int offs[256];
  const int t = threadIdx.x;
  const int CH = (N_NODES + 255) / 256;  // 79
  const int s = t * CH;
  const int e = min(s + CH, N_NODES);
  int sum = 0;
  for (int i = s; i < e; ++i) sum += deg[i];
  partial[t] = sum;
  __syncthreads();
  if (t == 0) {
    int run = 0;
    for (int i = 0; i < 256; ++i) { offs[i] = run; run += partial[i]; }
  }
  __syncthreads();
  int run = offs[t];
  for (int i = s; i < e; ++i) {
    rowp[i] = run; cur[i] = run; run += deg[i];
  }
  if (t == 0) rowp[N_NODES] = TOT_E;
}

__global__ void scatter_kernel(const int* __restrict__ ei, int* __restrict__ cur,
                               int* __restrict__ colb) {
  int e = blockIdx.x * blockDim.x + threadIdx.x;
  if (e >= TOT_E) return;
  int src, dst;
  if (e < E_EDGES) { src = ei[e]; dst = ei[E_EDGES + e]; }
  else             { src = dst = e - E_EDGES; }
  int pos = atomicAdd(&cur[dst], 1);
  colb[pos] = src;
}

// ---------- f32 tiled GEMM: C[M,256] = A[M,256] @ B[256,256] ----------
__global__ __launch_bounds__(256)
void gemm_f32_kernel(const float* __restrict__ A, const float* __restrict__ B,
                     float* __restrict__ C, int M) {
  __shared__ float As[16][64];
  __shared__ float Bs[16][64];
  const int tid = threadIdx.x;
  const int tx = tid & 15, ty = tid >> 4;
  const int row0 = blockIdx.y * 64, col0 = blockIdx.x * 64;
  const int am  = tid >> 2;           // 0..63 row of A tile
  const int ak  = (tid & 3) << 2;     // 0,4,8,12 k0 of A tile
  const int bkr = tid >> 4;           // 0..15 k of B tile
  const int bn0 = (tid & 15) << 2;    // 0..60 n0 of B tile
  const int ar = row0 + am;
  const bool arow_ok = (ar < M);
  float acc[4][4] = {{0.f}};
  for (int kk = 0; kk < 256; kk += 16) {
    float4 av = arow_ok ? *reinterpret_cast<const float4*>(&A[ar * 256 + kk + ak])
                        : make_float4(0.f, 0.f, 0.f, 0.f);
    As[ak + 0][am] = av.x; As[ak + 1][am] = av.y;
    As[ak + 2][am] = av.z; As[ak + 3][am] = av.w;
    *reinterpret_cast<float4*>(&Bs[bkr][bn0]) =
        *reinterpret_cast<const float4*>(&B[(kk + bkr) * 256 + col0 + bn0]);
    __syncthreads();
#pragma unroll
    for (int k = 0; k < 16; ++k) {
      float4 a = *reinterpret_cast<const float4*>(&As[k][ty << 2]);
      float4 b = *reinterpret_cast<const float4*>(&Bs[k][tx << 2]);
      acc[0][0] += a.x * b.x; acc[0][1] += a.x * b.y; acc[0][2] += a.x * b.z; acc[0][3] += a.x * b.w;
      acc[1][0] += a.y * b.x; acc[1][1] += a.y * b.y; acc[1][2] += a.y * b.z; acc[1][3] += a.y * b.w;
      acc[2][0] += a.z * b.x; acc[2][1] += a.z * b.y; acc[2][2] += a.z * b.z; acc[2][3] += a.z * b.w;
      acc[3][0] += a.w * b.x; acc[3][1] += a.w * b.y; acc[3][2] += a.w * b.z; acc[3][3] += a.w * b.w;
    }
    __syncthreads();
  }
#pragma unroll
  for (int i = 0; i < 4; ++i) {
    int r = row0 + (ty << 2) + i;
    if (r < M) {
      *reinterpret_cast<float4*>(&C[r * 256 + col0 + (tx << 2)]) =
          make_float4(acc[i][0], acc[i][1], acc[i][2], acc[i][3]);
    }
  }
}

// ---------- per-node attention logits ----------
__global__ __launch_bounds__(256)
void alpha_kernel(const float* __restrict__ h, const float* __restrict__ a_src,
                  const float* __restrict__ a_dst, float* __restrict__ as_,
                  float* __restrict__ ad_) {
  const int n = blockIdx.x;
  const int t = threadIdx.x;
  const int head = t >> 6, lane = t & 63;
  float v = h[n * 256 + t];
  float ps = wave_sum(v * a_src[t]);
  float pd = wave_sum(v * a_dst[t]);
  if (lane == 0) { as_[n * 4 + head] = ps; ad_[n * 4 + head] = pd; }
}

// ---------- GAT aggregate + bias + LayerNorm (+residual) + ELU ----------
// One block per dst node. Edge logits computed ONCE per (edge,head) into LDS
// (lanes parallel over edges), online-softmax over chunks, pass B only does
// LDS-broadcast weight * gathered h row.
__global__ __launch_bounds__(256)
void aggregate_kernel(const float* __restrict__ h, const float* __restrict__ as_,
                      const float* __restrict__ ad_, const int* __restrict__ rowp,
                      const int* __restrict__ colb, const float* __restrict__ bias,
                      const float* __restrict__ gamma, const float* __restrict__ beta,
                      const float* __restrict__ resid, float* __restrict__ outbuf) {
  __shared__ float ew[CHUNK][NHEAD + 1];  // +1 pad: conflict-free strided reads
  __shared__ int   sidx[CHUNK];
  __shared__ float red[8];

  const int d = blockIdx.x;
  const int t = threadIdx.x;
  const int head = t >> 6, lane = t & 63;  // reduction/pass-B mapping
  const int shead = t & 3;                 // staging mapping (edge = t>>2)
  const int start = rowp[d];
  const int deg = rowp[d + 1] - start;
  const float ad_stage = ad_[d * 4 + shead];

  float m = -INFINITY;  // running max (per head-wave, lane-replicated)
  float z = 0.f;        // running denom
  float acc = 0.f;      // running weighted sum for channel t

  for (int base = 0; base < deg; base += CHUNK) {
    const int cnt = min(deg - base, CHUNK);
    // --- stage logits: thread t handles (edge t>>2 + 64j, head t&3) ---
#pragma unroll
    for (int jj = 0; jj < CHUNK / 64; ++jj) {
      int i = jj * 64 + (t >> 2);
      if (i < cnt) {
        int s = colb[start + base + i];
        float e = as_[s * 4 + shead] + ad_stage;
        e = (e >= 0.f) ? e : 0.2f * e;
        ew[i][shead] = e;
        if (shead == 0) sidx[i] = s;
      }
    }
    __syncthreads();
    // --- chunk max (wave per head) ---
    float mc = -INFINITY;
    for (int i = lane; i < cnt; i += 64) mc = fmaxf(mc, ew[i][head]);
    mc = wave_max(mc);
    float mnew = fmaxf(m, mc);
    float scale = (m == -INFINITY) ? 0.f : __expf(m - mnew);
    acc *= scale;
    z *= scale;
    m = mnew;
    // --- exp + denom; store weight back (same wave reads it in pass B) ---
    float zc = 0.f;
    for (int i = lane; i < cnt; i += 64) {
      float w = __expf(ew[i][head] - m);
      ew[i][head] = w;
      zc += w;
    }
    z += wave_sum(zc);
    // --- pass B: weighted gather ---
    for (int i = 0; i < cnt; ++i) {
      int s = sidx[i];
      float w = ew[i][head];
      acc += w * h[s * 256 + t];
    }
    __syncthreads();  // protect LDS reuse by next chunk
  }

  float val = acc * (1.f / (z + 1e-16f)) + bias[t];
  // LayerNorm over 256 (block-wide)
  float sv = wave_sum(val);
  float sq = wave_sum(val * val);
  if (lane == 0) { red[head] = sv; red[4 + head] = sq; }
  __syncthreads();
  float tot  = red[0] + red[1] + red[2] + red[3];
  float totq = red[4] + red[5] + red[6] + red[7];
  float mu  = tot * (1.f / 256.f);
  float var = totq * (1.f / 256.f) - mu * mu;
  float y = (val - mu) * rsqrtf(var + 1e-5f) * gamma[t] + beta[t];
  if (resid) y += resid[d * 256 + t];
  outbuf[d * 256 + t] = (y > 0.f) ? y : expm1f(y);
}

// ---------- pooling ----------
__global__ __launch_bounds__(256)
void score_kernel(const float* __restrict__ x2, const float* __restrict__ aw,
                  const float* __restrict__ ab, float* __restrict__ s) {
  int gid = blockIdx.x * blockDim.x + threadIdx.x;
  int n = gid >> 6, lane = gid & 63;
  if (n >= N_NODES) return;
  float4 xv = *reinterpret_cast<const float4*>(&x2[n * 256 + lane * 4]);
  float4 wv = *reinterpret_cast<const float4*>(&aw[lane * 4]);
  float p = xv.x * wv.x + xv.y * wv.y + xv.z * wv.z + xv.w * wv.w;
  p = wave_sum(p);
  if (lane == 0) s[n] = p + ab[0];
}

__global__ __launch_bounds__(256)
void softmax_reduce_kernel(const float* __restrict__ s, float* __restrict__ mz) {
  __shared__ float red[4];
  const int t = threadIdx.x, lane = t & 63, wid = t >> 6;
  float m = -INFINITY;
  for (int n = t; n < N_NODES; n += 256) m = fmaxf(m, s[n]);
  m = wave_max(m);
  if (lane == 0) red[wid] = m;
  __syncthreads();
  m = fmaxf(fmaxf(red[0], red[1]), fmaxf(red[2], red[3]));
  __syncthreads();
  float z = 0.f;
  for (int n = t; n < N_NODES; n += 256) z += __expf(s[n] - m);
  z = wave_sum(z);
  if (lane == 0) red[wid] = z;
  __syncthreads();
  if (t == 0) { mz[0] = m; mz[1] = red[0] + red[1] + red[2] + red[3]; }
}

__global__ __launch_bounds__(256)
void pool_partial_kernel(const float* __restrict__ x2, const float* __restrict__ s,
                         const float* __restrict__ mz, float* __restrict__ part) {
  const int t = threadIdx.x, b = blockIdx.x;
  const float m = mz[0];
  const float invz = 1.f / mz[1];
  float acc = 0.f;
  for (int n = b; n < N_NODES; n += 256) {
    float w = __expf(s[n] - m);
    acc += w * x2[n * 256 + t];
  }
  part[b * 256 + t] = acc * invz;
}

__global__ __launch_bounds__(256)
void pool_final_kernel(const float* __restrict__ part, float* __restrict__ out) {
  const int t = threadIdx.x;
  float acc = 0.f;
  for (int b = 0; b < 256; ++b) acc += part[b * 256 + t];
  out[t] = acc;
}

extern "C" void kernel_launch(void* const* d_in, const int* in_sizes, int n_in,
                              void* d_out, int out_size, void* d_ws, size_t ws_size,
                              hipStream_t stream) {
  const float* x      = (const float*)d_in[0];
  const int*   ei     = (const int*)d_in[1];
  const float* W1     = (const float*)d_in[2];
  const float* b1     = (const float*)d_in[3];
  const float* a_src1 = (const float*)d_in[4];
  const float* a_dst1 = (const float*)d_in[5];
  const float* W2     = (const float*)d_in[6];
  const float* b2     = (const float*)d_in[7];
  const float* a_src2 = (const float*)d_in[8];
  const float* a_dst2 = (const float*)d_in[9];
  const float* g1     = (const float*)d_in[10];
  const float* be1    = (const float*)d_in[11];
  const float* g2     = (const float*)d_in[12];
  const float* be2    = (const float*)d_in[13];
  const float* attn_w = (const float*)d_in[14];
  const float* attn_b = (const float*)d_in[15];
  float* out = (float*)d_out;

  char* p = (char*)d_ws;
  auto alloc = [&](size_t bytes) {
    char* r = p;
    p += (bytes + 255) & ~size_t(255);
    return r;
  };
  float* h    = (float*)alloc((size_t)N_NODES * 256 * 4);
  float* x1   = (float*)alloc((size_t)N_NODES * 256 * 4);
  float* x2   = (float*)alloc((size_t)N_NODES * 256 * 4);
  float* as_  = (float*)alloc((size_t)N_NODES * 4 * 4);
  float* ad_  = (float*)alloc((size_t)N_NODES * 4 * 4);
  float* sbuf = (float*)alloc((size_t)N_NODES * 4);
  float* mz   = (float*)alloc(256);
  float* part = (float*)alloc((size_t)256 * 256 * 4);
  int* deg    = (int*)alloc((size_t)N_NODES * 4);
  int* rowp   = (int*)alloc((size_t)(N_NODES + 1) * 4);
  int* cur    = (int*)alloc((size_t)N_NODES * 4);
  int* colb   = (int*)alloc((size_t)TOT_E * 4);

  const int EB = (TOT_E + 255) / 256;

  zero_int_kernel<<<(N_NODES + 255) / 256, 256, 0, stream>>>(deg, N_NODES);
  hist_kernel<<<EB, 256, 0, stream>>>(ei, deg);
  scan_kernel<<<1, 256, 0, stream>>>(deg, rowp, cur);
  scatter_kernel<<<EB, 256, 0, stream>>>(ei, cur, colb);

  dim3 ggrid(4, (N_NODES + 63) / 64);

  // layer 1
  gemm_f32_kernel<<<ggrid, 256, 0, stream>>>(x, W1, h, N_NODES);
  alpha_kernel<<<N_NODES, 256, 0, stream>>>(h, a_src1, a_dst1, as_, ad_);
  aggregate_kernel<<<N_NODES, 256, 0, stream>>>(h, as_, ad_, rowp, colb, b1, g1, be1,
                                                nullptr, x1);
  // layer 2
  gemm_f32_kernel<<<ggrid, 256, 0, stream>>>(x1, W2, h, N_NODES);
  alpha_kernel<<<N_NODES, 256, 0, stream>>>(h, a_src2, a_dst2, as_, ad_);
  aggregate_kernel<<<N_NODES, 256, 0, stream>>>(h, as_, ad_, rowp, colb, b2, g2, be2,
                                                x1, x2);
  // pooling
  score_kernel<<<(N_NODES * 64 + 255) / 256, 256, 0, stream>>>(x2, attn_w, attn_b, sbuf);
  softmax_reduce_kernel<<<1, 256, 0, stream>>>(sbuf, mz);
  pool_partial_kernel<<<256, 256, 0, stream>>>(x2, sbuf, mz, part);
  pool_final_kernel<<<1, 256, 0, stream>>>(part, out);
}

// Round 3
// 311.095 us; speedup vs baseline: 1.5153x; 1.2193x over previous
//
#include <hip/hip_runtime.h>
#include <math.h>

#define N_NODES 20000
#define E_EDGES 320000
#define TOT_E   (E_EDGES + N_NODES)
#define DHID    256
#define NHEAD   4
#define CHUNK   64    // edges staged in LDS per online-softmax chunk

typedef float f32x4 __attribute__((ext_vector_type(4)));
typedef short short8 __attribute__((ext_vector_type(8)));
typedef unsigned short ushort;

// ---------- helpers ----------
__device__ __forceinline__ float wave_sum(float v) {
#pragma unroll
  for (int off = 32; off; off >>= 1) v += __shfl_xor(v, off);
  return v;
}
__device__ __forceinline__ float wave_max(float v) {
#pragma unroll
  for (int off = 32; off; off >>= 1) v = fmaxf(v, __shfl_xor(v, off));
  return v;
}
__device__ __forceinline__ ushort f2bf(float f) {  // RNE f32 -> bf16
  unsigned u = __float_as_uint(f);
  u += 0x7fffu + ((u >> 16) & 1u);
  return (ushort)(u >> 16);
}
__device__ __forceinline__ float bf2f(ushort h) {
  return __uint_as_float(((unsigned)h) << 16);
}

// ---------- CSR build ----------
__global__ void zero_int_kernel(int* __restrict__ p, int n) {
  int i = blockIdx.x * blockDim.x + threadIdx.x;
  if (i < n) p[i] = 0;
}

__global__ void hist_kernel(const int* __restrict__ ei, int* __restrict__ deg) {
  int e = blockIdx.x * blockDim.x + threadIdx.x;
  if (e >= TOT_E) return;
  int dst = (e < E_EDGES) ? ei[E_EDGES + e] : (e - E_EDGES);
  atomicAdd(&deg[dst], 1);
}

__global__ void scan_kernel(const int* __restrict__ deg, int* __restrict__ rowp,
                            int* __restrict__ cur) {
  __shared__ int partial[256];
  __shared__ int offs[256];
  const int t = threadIdx.x;
  const int CH = (N_NODES + 255) / 256;
  const int s = t * CH;
  const int e = min(s + CH, N_NODES);
  int sum = 0;
  for (int i = s; i < e; ++i) sum += deg[i];
  partial[t] = sum;
  __syncthreads();
  if (t == 0) {
    int run = 0;
    for (int i = 0; i < 256; ++i) { offs[i] = run; run += partial[i]; }
  }
  __syncthreads();
  int run = offs[t];
  for (int i = s; i < e; ++i) {
    rowp[i] = run; cur[i] = run; run += deg[i];
  }
  if (t == 0) rowp[N_NODES] = TOT_E;
}

__global__ void scatter_kernel(const int* __restrict__ ei, int* __restrict__ cur,
                               int* __restrict__ colb) {
  int e = blockIdx.x * blockDim.x + threadIdx.x;
  if (e >= TOT_E) return;
  int src, dst;
  if (e < E_EDGES) { src = ei[e]; dst = ei[E_EDGES + e]; }
  else             { src = dst = e - E_EDGES; }
  int pos = atomicAdd(&cur[dst], 1);
  colb[pos] = src;
}

// ---------- W -> Wt (transposed bf16): Wt[n][k] = bf16(W[k][n]) ----------
__global__ __launch_bounds__(256)
void convw_kernel(const float* __restrict__ W1, const float* __restrict__ W2,
                  ushort* __restrict__ Wt1, ushort* __restrict__ Wt2) {
  const int b = blockIdx.x;
  const float* W = (b < 256) ? W1 : W2;
  ushort* Wt = (b < 256) ? Wt1 : Wt2;
  const int n = b & 255;
  const int k = threadIdx.x;
  Wt[n * 256 + k] = f2bf(W[k * 256 + n]);
}

// ---------- fused bf16-MFMA GEMM + alpha epilogue ----------
// h_bf16[M,256] = bf16(A_f32 @ W); as_[r][h] = h[r,h,:]·a_src[h,:]; same ad_.
// Block: 64 rows x 256 cols, 512 threads = 8 waves (wm in 0..1 rows, wn = head).
__global__ __launch_bounds__(512)
void gemm_alpha_kernel(const float* __restrict__ A, const ushort* __restrict__ Wt,
                       const float* __restrict__ asrc, const float* __restrict__ adst,
                       ushort* __restrict__ hout, float* __restrict__ as_,
                       float* __restrict__ ad_, int M) {
  // A tile: [4 kgroups][66 rows (pad)][8 bf16] granules of 16 B
  __shared__ ushort As_[4 * 66 * 8];
  __shared__ ushort hs[64 * 256];  // 32 KB repack buffer

  const int t = threadIdx.x;
  const int w = t >> 6;            // wave 0..7
  const int l = t & 63;            // lane
  const int wm = w >> 2;           // row half 0..1
  const int wn = w & 3;            // col quarter == head
  const int row0 = blockIdx.x * 64;

  f32x4 acc[2][4];
#pragma unroll
  for (int i = 0; i < 2; ++i)
#pragma unroll
    for (int j = 0; j < 4; ++j) acc[i][j] = (f32x4){0.f, 0.f, 0.f, 0.f};

  // staging coords: thread t loads A[row0 + r][kk + kh*4 .. +3]
  const int sr = t >> 3;        // 0..63
  const int skh = t & 7;        // 0..7 (4-float chunk)
  const bool row_ok = (row0 + sr) < M;
  const float* aptr = A + (size_t)(row0 + sr) * 256 + skh * 4;
  // LDS write: granule (skh>>1)*66 + sr, half (skh&1)
  ushort* wptr = &As_[(((skh >> 1) * 66 + sr) * 8) + (skh & 1) * 4];

  // B fragment base: lane reads Wt[wn*64 + 16j + (l&15)][kk + (l>>4)*8 ..+7]
  const ushort* bbase = Wt + (size_t)(wn * 64 + (l & 15)) * 256 + ((l >> 4) * 8);

  for (int kk = 0; kk < 256; kk += 32) {
    float4 av = row_ok ? *reinterpret_cast<const float4*>(aptr + kk)
                       : make_float4(0.f, 0.f, 0.f, 0.f);
    ushort u0 = f2bf(av.x), u1 = f2bf(av.y), u2 = f2bf(av.z), u3 = f2bf(av.w);
    wptr[0] = u0; wptr[1] = u1; wptr[2] = u2; wptr[3] = u3;
    __syncthreads();
    short8 bfrag[4];
#pragma unroll
    for (int j = 0; j < 4; ++j)
      bfrag[j] = *reinterpret_cast<const short8*>(bbase + kk + j * 16 * 256);
#pragma unroll
    for (int i = 0; i < 2; ++i) {
      const int arow = wm * 32 + i * 16 + (l & 15);
      short8 afrag = *reinterpret_cast<const short8*>(&As_[(((l >> 4) * 66 + arow) * 8)]);
#pragma unroll
      for (int j = 0; j < 4; ++j)
        acc[i][j] = __builtin_amdgcn_mfma_f32_16x16x32_bf16(afrag, bfrag[j], acc[i][j], 0, 0, 0);
    }
    __syncthreads();
  }

  // ---- alpha epilogue: wave (wm,wn) owns rows [32wm,32wm+32) of head wn ----
  float asj[4], adj[4];
#pragma unroll
  for (int j = 0; j < 4; ++j) {
    asj[j] = asrc[wn * 64 + j * 16 + (l & 15)];
    adj[j] = adst[wn * 64 + j * 16 + (l & 15)];
  }
#pragma unroll
  for (int i = 0; i < 2; ++i) {
#pragma unroll
    for (int q = 0; q < 4; ++q) {
      float ps = 0.f, pd = 0.f;
#pragma unroll
      for (int j = 0; j < 4; ++j) {
        ps += acc[i][j][q] * asj[j];
        pd += acc[i][j][q] * adj[j];
      }
#pragma unroll
      for (int off = 1; off < 16; off <<= 1) {
        ps += __shfl_xor(ps, off);
        pd += __shfl_xor(pd, off);
      }
      int row = row0 + wm * 32 + i * 16 + (l >> 4) * 4 + q;
      if ((l & 15) == 0 && row < M) {
        as_[row * 4 + wn] = ps;
        ad_[row * 4 + wn] = pd;
      }
    }
  }

  // ---- h repack: fragments -> LDS bf16 -> coalesced global ----
#pragma unroll
  for (int i = 0; i < 2; ++i)
#pragma unroll
    for (int j = 0; j < 4; ++j)
#pragma unroll
      for (int q = 0; q < 4; ++q) {
        int row = wm * 32 + i * 16 + (l >> 4) * 4 + q;
        int col = wn * 64 + j * 16 + (l & 15);
        hs[row * 256 + col] = f2bf(acc[i][j][q]);
      }
  __syncthreads();
#pragma unroll
  for (int g = 0; g < 4; ++g) {
    int gi = g * 512 + t;          // granule of 8 ushorts
    int row = gi >> 5;
    int slot = gi & 31;
    if (row0 + row < M) {
      *reinterpret_cast<short8*>(hout + (size_t)(row0 + row) * 256 + slot * 8) =
          *reinterpret_cast<const short8*>(&hs[row * 256 + slot * 8]);
    }
  }
}

// ---------- GAT aggregate + bias + LayerNorm (+residual) + ELU ----------
__global__ __launch_bounds__(256)
void aggregate_kernel(const ushort* __restrict__ h, const float* __restrict__ as_,
                      const float* __restrict__ ad_, const int* __restrict__ rowp,
                      const int* __restrict__ colb, const float* __restrict__ bias,
                      const float* __restrict__ gamma, const float* __restrict__ beta,
                      const float* __restrict__ resid, float* __restrict__ outbuf) {
  __shared__ float ew[CHUNK][NHEAD + 1];
  __shared__ int   sidx[CHUNK];
  __shared__ float red[8];

  const int d = blockIdx.x;
  const int t = threadIdx.x;
  const int head = t >> 6, lane = t & 63;
  const int shead = t & 3;
  const int start = rowp[d];
  const int deg = rowp[d + 1] - start;
  const float ad_stage = ad_[d * 4 + shead];

  float m = -INFINITY;
  float z = 0.f;
  float acc = 0.f;

  for (int base = 0; base < deg; base += CHUNK) {
    const int cnt = min(deg - base, CHUNK);
    {
      int i = t >> 2;
      if (i < cnt) {
        int s = colb[start + base + i];
        float e = as_[s * 4 + shead] + ad_stage;
        e = (e >= 0.f) ? e : 0.2f * e;
        ew[i][shead] = e;
        if (shead == 0) sidx[i] = s;
      }
    }
    __syncthreads();
    float mc = -INFINITY;
    if (lane < cnt) mc = ew[lane][head];
    mc = wave_max(mc);
    float mnew = fmaxf(m, mc);
    float scale = (m == -INFINITY) ? 0.f : __expf(m - mnew);
    acc *= scale;
    z *= scale;
    m = mnew;
    float zc = 0.f;
    if (lane < cnt) {
      float wv = __expf(ew[lane][head] - m);
      ew[lane][head] = wv;
      zc = wv;
    }
    z += wave_sum(zc);
    for (int i = 0; i < cnt; ++i) {
      int s = sidx[i];
      float wv = ew[i][head];
      acc += wv * bf2f(h[(size_t)s * 256 + t]);
    }
    __syncthreads();
  }

  float val = acc * (1.f / (z + 1e-16f)) + bias[t];
  float sv = wave_sum(val);
  float sq = wave_sum(val * val);
  if (lane == 0) { red[head] = sv; red[4 + head] = sq; }
  __syncthreads();
  float tot  = red[0] + red[1] + red[2] + red[3];
  float totq = red[4] + red[5] + red[6] + red[7];
  float mu  = tot * (1.f / 256.f);
  float var = totq * (1.f / 256.f) - mu * mu;
  float y = (val - mu) * rsqrtf(var + 1e-5f) * gamma[t] + beta[t];
  if (resid) y += resid[(size_t)d * 256 + t];
  outbuf[(size_t)d * 256 + t] = (y > 0.f) ? y : expm1f(y);
}

// ---------- pooling ----------
__global__ __launch_bounds__(256)
void score_kernel(const float* __restrict__ x2, const float* __restrict__ aw,
                  const float* __restrict__ ab, float* __restrict__ s) {
  int gid = blockIdx.x * blockDim.x + threadIdx.x;
  int n = gid >> 6, lane = gid & 63;
  if (n >= N_NODES) return;
  float4 xv = *reinterpret_cast<const float4*>(&x2[(size_t)n * 256 + lane * 4]);
  float4 wv = *reinterpret_cast<const float4*>(&aw[lane * 4]);
  float p = xv.x * wv.x + xv.y * wv.y + xv.z * wv.z + xv.w * wv.w;
  p = wave_sum(p);
  if (lane == 0) s[n] = p + ab[0];
}

__global__ __launch_bounds__(256)
void softmax_reduce_kernel(const float* __restrict__ s, float* __restrict__ mz) {
  __shared__ float red[4];
  const int t = threadIdx.x, lane = t & 63, wid = t >> 6;
  float m = -INFINITY;
  for (int n = t; n < N_NODES; n += 256) m = fmaxf(m, s[n]);
  m = wave_max(m);
  if (lane == 0) red[wid] = m;
  __syncthreads();
  m = fmaxf(fmaxf(red[0], red[1]), fmaxf(red[2], red[3]));
  __syncthreads();
  float z = 0.f;
  for (int n = t; n < N_NODES; n += 256) z += __expf(s[n] - m);
  z = wave_sum(z);
  if (lane == 0) red[wid] = z;
  __syncthreads();
  if (t == 0) { mz[0] = m; mz[1] = red[0] + red[1] + red[2] + red[3]; }
}

__global__ __launch_bounds__(256)
void pool_partial_kernel(const float* __restrict__ x2, const float* __restrict__ s,
                         const float* __restrict__ mz, float* __restrict__ part) {
  const int t = threadIdx.x, b = blockIdx.x;
  const float m = mz[0];
  const float invz = 1.f / mz[1];
  float acc = 0.f;
  for (int n = b; n < N_NODES; n += 256) {
    float w = __expf(s[n] - m);
    acc += w * x2[(size_t)n * 256 + t];
  }
  part[b * 256 + t] = acc * invz;
}

__global__ __launch_bounds__(256)
void pool_final_kernel(const float* __restrict__ part, float* __restrict__ out) {
  const int t = threadIdx.x;
  float acc = 0.f;
  for (int b = 0; b < 256; ++b) acc += part[b * 256 + t];
  out[t] = acc;
}

extern "C" void kernel_launch(void* const* d_in, const int* in_sizes, int n_in,
                              void* d_out, int out_size, void* d_ws, size_t ws_size,
                              hipStream_t stream) {
  const float* x      = (const float*)d_in[0];
  const int*   ei     = (const int*)d_in[1];
  const float* W1     = (const float*)d_in[2];
  const float* b1     = (const float*)d_in[3];
  const float* a_src1 = (const float*)d_in[4];
  const float* a_dst1 = (const float*)d_in[5];
  const float* W2     = (const float*)d_in[6];
  const float* b2     = (const float*)d_in[7];
  const float* a_src2 = (const float*)d_in[8];
  const float* a_dst2 = (const float*)d_in[9];
  const float* g1     = (const float*)d_in[10];
  const float* be1    = (const float*)d_in[11];
  const float* g2     = (const float*)d_in[12];
  const float* be2    = (const float*)d_in[13];
  const float* attn_w = (const float*)d_in[14];
  const float* attn_b = (const float*)d_in[15];
  float* out = (float*)d_out;

  char* p = (char*)d_ws;
  auto alloc = [&](size_t bytes) {
    char* r = p;
    p += (bytes + 255) & ~size_t(255);
    return r;
  };
  ushort* h   = (ushort*)alloc((size_t)N_NODES * 256 * 2);
  float* x1   = (float*)alloc((size_t)N_NODES * 256 * 4);
  float* x2   = (float*)alloc((size_t)N_NODES * 256 * 4);
  float* as_  = (float*)alloc((size_t)N_NODES * 4 * 4);
  float* ad_  = (float*)alloc((size_t)N_NODES * 4 * 4);
  float* sbuf = (float*)alloc((size_t)N_NODES * 4);
  float* mz   = (float*)alloc(256);
  float* part = (float*)alloc((size_t)256 * 256 * 4);
  ushort* wt1 = (ushort*)alloc((size_t)256 * 256 * 2);
  ushort* wt2 = (ushort*)alloc((size_t)256 * 256 * 2);
  int* deg    = (int*)alloc((size_t)N_NODES * 4);
  int* rowp   = (int*)alloc((size_t)(N_NODES + 1) * 4);
  int* cur    = (int*)alloc((size_t)N_NODES * 4);
  int* colb   = (int*)alloc((size_t)TOT_E * 4);

  const int EB = (TOT_E + 255) / 256;
  const int GB = (N_NODES + 63) / 64;  // 313

  zero_int_kernel<<<(N_NODES + 255) / 256, 256, 0, stream>>>(deg, N_NODES);
  hist_kernel<<<EB, 256, 0, stream>>>(ei, deg);
  convw_kernel<<<512, 256, 0, stream>>>(W1, W2, wt1, wt2);
  scan_kernel<<<1, 256, 0, stream>>>(deg, rowp, cur);
  scatter_kernel<<<EB, 256, 0, stream>>>(ei, cur, colb);

  // layer 1
  gemm_alpha_kernel<<<GB, 512, 0, stream>>>(x, wt1, a_src1, a_dst1, h, as_, ad_, N_NODES);
  aggregate_kernel<<<N_NODES, 256, 0, stream>>>(h, as_, ad_, rowp, colb, b1, g1, be1,
                                                nullptr, x1);
  // layer 2
  gemm_alpha_kernel<<<GB, 512, 0, stream>>>(x1, wt2, a_src2, a_dst2, h, as_, ad_, N_NODES);
  aggregate_kernel<<<N_NODES, 256, 0, stream>>>(h, as_, ad_, rowp, colb, b2, g2, be2,
                                                x1, x2);
  // pooling
  score_kernel<<<(N_NODES * 64 + 255) / 256, 256, 0, stream>>>(x2, attn_w, attn_b, sbuf);
  softmax_reduce_kernel<<<1, 256, 0, stream>>>(sbuf, mz);
  pool_partial_kernel<<<256, 256, 0, stream>>>(x2, sbuf, mz, part);
  pool_final_kernel<<<1, 256, 0, stream>>>(part, out);
}

// Round 4
// 272.392 us; speedup vs baseline: 1.7306x; 1.1421x over previous
//
#include <hip/hip_runtime.h>
#include <math.h>

#define N_NODES 20000
#define E_EDGES 320000
#define TOT_E   (E_EDGES + N_NODES)
#define DHID    256
#define NHEAD   4
#define CHUNK   64    // edges staged in LDS per online-softmax chunk

typedef float f32x4 __attribute__((ext_vector_type(4)));
typedef short short8 __attribute__((ext_vector_type(8)));
typedef unsigned short ushort;

// ---------- helpers ----------
__device__ __forceinline__ float wave_sum(float v) {
#pragma unroll
  for (int off = 32; off; off >>= 1) v += __shfl_xor(v, off);
  return v;
}
__device__ __forceinline__ float wave_max(float v) {
#pragma unroll
  for (int off = 32; off; off >>= 1) v = fmaxf(v, __shfl_xor(v, off));
  return v;
}
__device__ __forceinline__ ushort f2bf(float f) {  // RNE f32 -> bf16
  unsigned u = __float_as_uint(f);
  u += 0x7fffu + ((u >> 16) & 1u);
  return (ushort)(u >> 16);
}
__device__ __forceinline__ float bf2f(ushort h) {
  return __uint_as_float(((unsigned)h) << 16);
}

// ---------- CSR build ----------
__global__ void zero_int_kernel(int* __restrict__ p, int n) {
  int i = blockIdx.x * blockDim.x + threadIdx.x;
  if (i < n) p[i] = 0;
}

__global__ void hist_kernel(const int* __restrict__ ei, int* __restrict__ deg) {
  int e = blockIdx.x * blockDim.x + threadIdx.x;
  if (e >= TOT_E) return;
  int dst = (e < E_EDGES) ? ei[E_EDGES + e] : (e - E_EDGES);
  atomicAdd(&deg[dst], 1);
}

__global__ void scan_kernel(const int* __restrict__ deg, int* __restrict__ rowp,
                            int* __restrict__ cur) {
  __shared__ int partial[256];
  __shared__ int offs[256];
  const int t = threadIdx.x;
  const int CH = (N_NODES + 255) / 256;
  const int s = t * CH;
  const int e = min(s + CH, N_NODES);
  int sum = 0;
  for (int i = s; i < e; ++i) sum += deg[i];
  partial[t] = sum;
  __syncthreads();
  if (t == 0) {
    int run = 0;
    for (int i = 0; i < 256; ++i) { offs[i] = run; run += partial[i]; }
  }
  __syncthreads();
  int run = offs[t];
  for (int i = s; i < e; ++i) {
    rowp[i] = run; cur[i] = run; run += deg[i];
  }
  if (t == 0) rowp[N_NODES] = TOT_E;
}

__global__ void scatter_kernel(const int* __restrict__ ei, int* __restrict__ cur,
                               int* __restrict__ colb) {
  int e = blockIdx.x * blockDim.x + threadIdx.x;
  if (e >= TOT_E) return;
  int src, dst;
  if (e < E_EDGES) { src = ei[e]; dst = ei[E_EDGES + e]; }
  else             { src = dst = e - E_EDGES; }
  int pos = atomicAdd(&cur[dst], 1);
  colb[pos] = src;
}

// ---------- W -> Wt (transposed bf16): Wt[n][k] = bf16(W[k][n]) ----------
__global__ __launch_bounds__(256)
void convw_kernel(const float* __restrict__ W1, const float* __restrict__ W2,
                  ushort* __restrict__ Wt1, ushort* __restrict__ Wt2) {
  const int b = blockIdx.x;
  const float* W = (b < 256) ? W1 : W2;
  ushort* Wt = (b < 256) ? Wt1 : Wt2;
  const int n = b & 255;
  const int k = threadIdx.x;
  Wt[n * 256 + k] = f2bf(W[k * 256 + n]);
}

// ---------- x f32 -> bf16 ----------
__global__ __launch_bounds__(256)
void convx_kernel(const float* __restrict__ x, ushort* __restrict__ xb) {
  int idx = blockIdx.x * 256 + threadIdx.x;  // granule of 8
  size_t base = (size_t)idx * 8;
  float4 a = *reinterpret_cast<const float4*>(x + base);
  float4 b = *reinterpret_cast<const float4*>(x + base + 4);
  short8 o;
  o[0] = f2bf(a.x); o[1] = f2bf(a.y); o[2] = f2bf(a.z); o[3] = f2bf(a.w);
  o[4] = f2bf(b.x); o[5] = f2bf(b.y); o[6] = f2bf(b.z); o[7] = f2bf(b.w);
  *reinterpret_cast<short8*>(xb + base) = o;
}

// ---------- bf16-MFMA GEMM (barrier-free K-loop) + alpha epilogue ----------
// h[M,256] = bf16(Ab @ W); as_/ad_ per-row-head dots.
// Block: 32 rows x 256 cols, 256 threads = 4 waves; wave w = head/col-quarter.
// A and B fragments read DIRECTLY from global (L1/L2-hot), no LDS in K-loop.
__global__ __launch_bounds__(256)
void gemm_alpha_kernel(const ushort* __restrict__ Ab, const ushort* __restrict__ Wt,
                       const float* __restrict__ asrc, const float* __restrict__ adst,
                       ushort* __restrict__ hout, float* __restrict__ as_,
                       float* __restrict__ ad_) {
  __shared__ ushort hs[32 * 256];  // 16 KB repack buffer

  const int t = threadIdx.x;
  const int w = t >> 6;            // wave 0..3 == head == col quarter
  const int l = t & 63;
  const int row0 = blockIdx.x * 32;

  const ushort* abase = Ab + (size_t)(row0 + (l & 15)) * 256 + ((l >> 4) * 8);
  const ushort* bbase = Wt + (size_t)(w * 64 + (l & 15)) * 256 + ((l >> 4) * 8);

  f32x4 acc[2][4];
#pragma unroll
  for (int i = 0; i < 2; ++i)
#pragma unroll
    for (int j = 0; j < 4; ++j) acc[i][j] = (f32x4){0.f, 0.f, 0.f, 0.f};

#pragma unroll 2
  for (int kk = 0; kk < 256; kk += 32) {
    short8 a0 = *reinterpret_cast<const short8*>(abase + kk);
    short8 a1 = *reinterpret_cast<const short8*>(abase + 16 * 256 + kk);
    short8 b0 = *reinterpret_cast<const short8*>(bbase + kk);
    short8 b1 = *reinterpret_cast<const short8*>(bbase + kk + 16 * 256);
    short8 b2 = *reinterpret_cast<const short8*>(bbase + kk + 32 * 256);
    short8 b3 = *reinterpret_cast<const short8*>(bbase + kk + 48 * 256);
    acc[0][0] = __builtin_amdgcn_mfma_f32_16x16x32_bf16(a0, b0, acc[0][0], 0, 0, 0);
    acc[0][1] = __builtin_amdgcn_mfma_f32_16x16x32_bf16(a0, b1, acc[0][1], 0, 0, 0);
    acc[0][2] = __builtin_amdgcn_mfma_f32_16x16x32_bf16(a0, b2, acc[0][2], 0, 0, 0);
    acc[0][3] = __builtin_amdgcn_mfma_f32_16x16x32_bf16(a0, b3, acc[0][3], 0, 0, 0);
    acc[1][0] = __builtin_amdgcn_mfma_f32_16x16x32_bf16(a1, b0, acc[1][0], 0, 0, 0);
    acc[1][1] = __builtin_amdgcn_mfma_f32_16x16x32_bf16(a1, b1, acc[1][1], 0, 0, 0);
    acc[1][2] = __builtin_amdgcn_mfma_f32_16x16x32_bf16(a1, b2, acc[1][2], 0, 0, 0);
    acc[1][3] = __builtin_amdgcn_mfma_f32_16x16x32_bf16(a1, b3, acc[1][3], 0, 0, 0);
  }

  // ---- alpha epilogue: wave w owns head w, rows row0..row0+31 ----
  float asj[4], adj[4];
#pragma unroll
  for (int j = 0; j < 4; ++j) {
    asj[j] = asrc[w * 64 + j * 16 + (l & 15)];
    adj[j] = adst[w * 64 + j * 16 + (l & 15)];
  }
#pragma unroll
  for (int i = 0; i < 2; ++i) {
#pragma unroll
    for (int q = 0; q < 4; ++q) {
      float ps = 0.f, pd = 0.f;
#pragma unroll
      for (int j = 0; j < 4; ++j) {
        ps += acc[i][j][q] * asj[j];
        pd += acc[i][j][q] * adj[j];
      }
#pragma unroll
      for (int off = 1; off < 16; off <<= 1) {
        ps += __shfl_xor(ps, off);
        pd += __shfl_xor(pd, off);
      }
      int row = row0 + i * 16 + (l >> 4) * 4 + q;
      if ((l & 15) == 0) {
        as_[row * 4 + w] = ps;
        ad_[row * 4 + w] = pd;
      }
    }
  }

  // ---- h repack: fragments -> LDS bf16 -> coalesced global ----
#pragma unroll
  for (int i = 0; i < 2; ++i)
#pragma unroll
    for (int j = 0; j < 4; ++j)
#pragma unroll
      for (int q = 0; q < 4; ++q) {
        int row = i * 16 + (l >> 4) * 4 + q;
        int col = w * 64 + j * 16 + (l & 15);
        hs[row * 256 + col] = f2bf(acc[i][j][q]);
      }
  __syncthreads();
#pragma unroll
  for (int g = 0; g < 4; ++g) {
    int gi = g * 256 + t;  // granule of 8 ushorts; 32 rows x 32 slots
    int row = gi >> 5;
    int slot = gi & 31;
    *reinterpret_cast<short8*>(hout + (size_t)(row0 + row) * 256 + slot * 8) =
        *reinterpret_cast<const short8*>(&hs[row * 256 + slot * 8]);
  }
}

// ---------- GAT aggregate + bias + LayerNorm (+bf16 residual) + ELU ----------
// Vectorized gather: 32 threads/row (short8 = 8 channels each), 8 edges in
// flight (t>>5 = edge residue), LDS transpose-reduce at the end.
__global__ __launch_bounds__(256)
void aggregate_kernel(const ushort* __restrict__ h, const float* __restrict__ as_,
                      const float* __restrict__ ad_, const int* __restrict__ rowp,
                      const int* __restrict__ colb, const float* __restrict__ bias,
                      const float* __restrict__ gamma, const float* __restrict__ beta,
                      const ushort* __restrict__ residb, float* __restrict__ outf,
                      ushort* __restrict__ outb, const float* __restrict__ aw,
                      const float* __restrict__ ab, float* __restrict__ score) {
  __shared__ float ew[CHUNK][NHEAD + 1];
  __shared__ int   sidx[CHUNK];
  __shared__ float red[8];
  __shared__ float rs[NHEAD];
  __shared__ float part[8][256];  // 8 KB

  const int d = blockIdx.x;
  const int t = threadIdx.x;
  const int head = t >> 6, lane = t & 63;  // softmax/epilogue mapping
  const int shead = t & 3;                 // staging mapping
  const int g = t >> 5;                    // gather: edge residue 0..7
  const int cb = t & 31;                   // channel block (8 ch)
  const int ghead = cb >> 3;               // head owning gather channels
  const int start = rowp[d];
  const int deg = rowp[d + 1] - start;
  const float ad_stage = ad_[d * 4 + shead];

  float m = -INFINITY, z = 0.f;
  float acc[8];
#pragma unroll
  for (int k = 0; k < 8; ++k) acc[k] = 0.f;

  for (int base = 0; base < deg; base += CHUNK) {
    const int cnt = min(deg - base, CHUNK);
    {  // stage logits: thread t -> (edge t>>2, head t&3)
      int i = t >> 2;
      if (i < cnt) {
        int s = colb[start + base + i];
        float e = as_[s * 4 + shead] + ad_stage;
        e = (e >= 0.f) ? e : 0.2f * e;
        ew[i][shead] = e;
        if (shead == 0) sidx[i] = s;
      }
    }
    __syncthreads();
    // online softmax (wave per head)
    float mc = (lane < cnt) ? ew[lane][head] : -INFINITY;
    mc = wave_max(mc);
    float mnew = fmaxf(m, mc);
    float sc = (m == -INFINITY) ? 0.f : __expf(m - mnew);
    z *= sc;
    m = mnew;
    float zc = 0.f;
    if (lane < cnt) {
      float wv = __expf(ew[lane][head] - m);
      ew[lane][head] = wv;
      zc = wv;
    }
    z += wave_sum(zc);
    if (lane == 0) rs[head] = sc;
    __syncthreads();
    // vectorized gather
    float s0 = rs[ghead];
#pragma unroll
    for (int k = 0; k < 8; ++k) acc[k] *= s0;
    for (int i = g; i < cnt; i += 8) {
      int s = sidx[i];
      float wv = ew[i][ghead];
      uint4 hv = *reinterpret_cast<const uint4*>(h + (size_t)s * 256 + cb * 8);
      acc[0] += wv * __uint_as_float(hv.x << 16);
      acc[1] += wv * __uint_as_float(hv.x & 0xffff0000u);
      acc[2] += wv * __uint_as_float(hv.y << 16);
      acc[3] += wv * __uint_as_float(hv.y & 0xffff0000u);
      acc[4] += wv * __uint_as_float(hv.z << 16);
      acc[5] += wv * __uint_as_float(hv.z & 0xffff0000u);
      acc[6] += wv * __uint_as_float(hv.w << 16);
      acc[7] += wv * __uint_as_float(hv.w & 0xffff0000u);
    }
    __syncthreads();  // protect ew/sidx for next chunk
  }

  // transpose-reduce partials: channel t = sum over 8 edge residues
#pragma unroll
  for (int k = 0; k < 8; ++k) part[g][cb * 8 + k] = acc[k];
  __syncthreads();
  float val = 0.f;
#pragma unroll
  for (int gg = 0; gg < 8; ++gg) val += part[gg][t];
  val = val * (1.f / (z + 1e-16f)) + bias[t];

  // LayerNorm over 256
  float sv = wave_sum(val);
  float sq = wave_sum(val * val);
  if (lane == 0) { red[head] = sv; red[4 + head] = sq; }
  __syncthreads();
  float tot  = red[0] + red[1] + red[2] + red[3];
  float totq = red[4] + red[5] + red[6] + red[7];
  float mu  = tot * (1.f / 256.f);
  float var = totq * (1.f / 256.f) - mu * mu;
  float y = (val - mu) * rsqrtf(var + 1e-5f) * gamma[t] + beta[t];
  if (residb) y += bf2f(residb[(size_t)d * 256 + t]);
  y = (y > 0.f) ? y : expm1f(y);
  if (outf) outf[(size_t)d * 256 + t] = y;
  if (outb) outb[(size_t)d * 256 + t] = f2bf(y);

  // fused pooling score: score[d] = sum_t y*aw[t] + ab
  if (score) {
    float sp = wave_sum(y * aw[t]);
    __syncthreads();
    if (lane == 0) red[head] = sp;
    __syncthreads();
    if (t == 0) score[d] = red[0] + red[1] + red[2] + red[3] + ab[0];
  }
}

// ---------- pooling ----------
__global__ __launch_bounds__(256)
void softmax_reduce_kernel(const float* __restrict__ s, float* __restrict__ mz) {
  __shared__ float red[4];
  const int t = threadIdx.x, lane = t & 63, wid = t >> 6;
  float m = -INFINITY;
  for (int n4 = t; n4 < N_NODES / 4; n4 += 256) {
    float4 v = *reinterpret_cast<const float4*>(s + n4 * 4);
    m = fmaxf(m, fmaxf(fmaxf(v.x, v.y), fmaxf(v.z, v.w)));
  }
  m = wave_max(m);
  if (lane == 0) red[wid] = m;
  __syncthreads();
  m = fmaxf(fmaxf(red[0], red[1]), fmaxf(red[2], red[3]));
  __syncthreads();
  float z = 0.f;
  for (int n4 = t; n4 < N_NODES / 4; n4 += 256) {
    float4 v = *reinterpret_cast<const float4*>(s + n4 * 4);
    z += __expf(v.x - m) + __expf(v.y - m) + __expf(v.z - m) + __expf(v.w - m);
  }
  z = wave_sum(z);
  if (lane == 0) red[wid] = z;
  __syncthreads();
  if (t == 0) { mz[0] = m; mz[1] = red[0] + red[1] + red[2] + red[3]; }
}

__global__ __launch_bounds__(256)
void pool_partial_kernel(const float* __restrict__ x2, const float* __restrict__ s,
                         const float* __restrict__ mz, float* __restrict__ part) {
  __shared__ float red4[4][256];
  const int t = threadIdx.x, b = blockIdx.x;
  const int c4 = t & 63, rsub = t >> 6;
  const float m = mz[0];
  const float invz = 1.f / mz[1];
  f32x4 acc = (f32x4){0.f, 0.f, 0.f, 0.f};
  for (int n = b * 4 + rsub; n < N_NODES; n += 1024) {
    float w = __expf(s[n] - m);
    float4 xv = *reinterpret_cast<const float4*>(&x2[(size_t)n * 256 + c4 * 4]);
    acc[0] += w * xv.x; acc[1] += w * xv.y; acc[2] += w * xv.z; acc[3] += w * xv.w;
  }
#pragma unroll
  for (int k = 0; k < 4; ++k) red4[rsub][c4 * 4 + k] = acc[k];
  __syncthreads();
  if (t < 256) {
    float v = red4[0][t] + red4[1][t] + red4[2][t] + red4[3][t];
    part[b * 256 + t] = v * invz;
  }
}

__global__ __launch_bounds__(256)
void pool_final_kernel(const float* __restrict__ part, float* __restrict__ out) {
  const int t = threadIdx.x;
  float acc = 0.f;
  for (int b = 0; b < 256; ++b) acc += part[b * 256 + t];
  out[t] = acc;
}

extern "C" void kernel_launch(void* const* d_in, const int* in_sizes, int n_in,
                              void* d_out, int out_size, void* d_ws, size_t ws_size,
                              hipStream_t stream) {
  const float* x      = (const float*)d_in[0];
  const int*   ei     = (const int*)d_in[1];
  const float* W1     = (const float*)d_in[2];
  const float* b1     = (const float*)d_in[3];
  const float* a_src1 = (const float*)d_in[4];
  const float* a_dst1 = (const float*)d_in[5];
  const float* W2     = (const float*)d_in[6];
  const float* b2     = (const float*)d_in[7];
  const float* a_src2 = (const float*)d_in[8];
  const float* a_dst2 = (const float*)d_in[9];
  const float* g1     = (const float*)d_in[10];
  const float* be1    = (const float*)d_in[11];
  const float* g2     = (const float*)d_in[12];
  const float* be2    = (const float*)d_in[13];
  const float* attn_w = (const float*)d_in[14];
  const float* attn_b = (const float*)d_in[15];
  float* out = (float*)d_out;

  char* p = (char*)d_ws;
  auto alloc = [&](size_t bytes) {
    char* r = p;
    p += (bytes + 255) & ~size_t(255);
    return r;
  };
  ushort* h   = (ushort*)alloc((size_t)N_NODES * 256 * 2);
  ushort* xb  = (ushort*)alloc((size_t)N_NODES * 256 * 2);
  ushort* xb1 = (ushort*)alloc((size_t)N_NODES * 256 * 2);
  float* x2   = (float*)alloc((size_t)N_NODES * 256 * 4);
  float* as_  = (float*)alloc((size_t)N_NODES * 4 * 4);
  float* ad_  = (float*)alloc((size_t)N_NODES * 4 * 4);
  float* sbuf = (float*)alloc((size_t)N_NODES * 4);
  float* mz   = (float*)alloc(256);
  float* part = (float*)alloc((size_t)256 * 256 * 4);
  ushort* wt1 = (ushort*)alloc((size_t)256 * 256 * 2);
  ushort* wt2 = (ushort*)alloc((size_t)256 * 256 * 2);
  int* deg    = (int*)alloc((size_t)N_NODES * 4);
  int* rowp   = (int*)alloc((size_t)(N_NODES + 1) * 4);
  int* cur    = (int*)alloc((size_t)N_NODES * 4);
  int* colb   = (int*)alloc((size_t)TOT_E * 4);

  const int EB = (TOT_E + 255) / 256;
  const int GB = N_NODES / 32;  // 625 exactly

  zero_int_kernel<<<(N_NODES + 255) / 256, 256, 0, stream>>>(deg, N_NODES);
  hist_kernel<<<EB, 256, 0, stream>>>(ei, deg);
  convw_kernel<<<512, 256, 0, stream>>>(W1, W2, wt1, wt2);
  convx_kernel<<<N_NODES * 256 / 8 / 256, 256, 0, stream>>>(x, xb);
  scan_kernel<<<1, 256, 0, stream>>>(deg, rowp, cur);
  scatter_kernel<<<EB, 256, 0, stream>>>(ei, cur, colb);

  // layer 1: out = bf16 xb1 only (also serves as residual + layer-2 A)
  gemm_alpha_kernel<<<GB, 256, 0, stream>>>(xb, wt1, a_src1, a_dst1, h, as_, ad_);
  aggregate_kernel<<<N_NODES, 256, 0, stream>>>(h, as_, ad_, rowp, colb, b1, g1, be1,
                                                nullptr, nullptr, xb1,
                                                nullptr, nullptr, nullptr);
  // layer 2: out = f32 x2 + fused score
  gemm_alpha_kernel<<<GB, 256, 0, stream>>>(xb1, wt2, a_src2, a_dst2, h, as_, ad_);
  aggregate_kernel<<<N_NODES, 256, 0, stream>>>(h, as_, ad_, rowp, colb, b2, g2, be2,
                                                xb1, x2, nullptr,
                                                attn_w, attn_b, sbuf);
  // pooling
  softmax_reduce_kernel<<<1, 256, 0, stream>>>(sbuf, mz);
  pool_partial_kernel<<<256, 256, 0, stream>>>(x2, sbuf, mz, part);
  pool_final_kernel<<<1, 256, 0, stream>>>(part, out);
}

// Round 5
// 254.621 us; speedup vs baseline: 1.8514x; 1.0698x over previous
//
#include <hip/hip_runtime.h>
#include <math.h>

#define N_NODES 20000
#define E_EDGES 320000
#define TOT_E   (E_EDGES + N_NODES)
#define DHID    256
#define NHEAD   4

typedef float f32x4 __attribute__((ext_vector_type(4)));
typedef short short8 __attribute__((ext_vector_type(8)));
typedef unsigned short ushort;

// ---------- helpers ----------
__device__ __forceinline__ float wave_sum(float v) {
#pragma unroll
  for (int off = 32; off; off >>= 1) v += __shfl_xor(v, off);
  return v;
}
__device__ __forceinline__ ushort f2bf(float f) {  // RNE f32 -> bf16
  unsigned u = __float_as_uint(f);
  u += 0x7fffu + ((u >> 16) & 1u);
  return (ushort)(u >> 16);
}
__device__ __forceinline__ float bflo(unsigned u) {
  return __uint_as_float(u << 16);
}
__device__ __forceinline__ float bfhi(unsigned u) {
  return __uint_as_float(u & 0xffff0000u);
}

// ---------- CSR build ----------
__global__ void hist_kernel(const int* __restrict__ ei, int* __restrict__ deg) {
  int e = blockIdx.x * blockDim.x + threadIdx.x;
  if (e >= TOT_E) return;
  int dst = (e < E_EDGES) ? ei[E_EDGES + e] : (e - E_EDGES);
  atomicAdd(&deg[dst], 1);
}

__global__ void scan_kernel(const int* __restrict__ deg, int* __restrict__ rowp,
                            int* __restrict__ cur) {
  __shared__ int partial[256];
  __shared__ int offs[256];
  const int t = threadIdx.x;
  const int CH = (N_NODES + 255) / 256;
  const int s = t * CH;
  const int e = min(s + CH, N_NODES);
  int sum = 0;
  for (int i = s; i < e; ++i) sum += deg[i];
  partial[t] = sum;
  __syncthreads();
  if (t == 0) {
    int run = 0;
    for (int i = 0; i < 256; ++i) { offs[i] = run; run += partial[i]; }
  }
  __syncthreads();
  int run = offs[t];
  for (int i = s; i < e; ++i) {
    rowp[i] = run; cur[i] = run; run += deg[i];
  }
  if (t == 0) rowp[N_NODES] = TOT_E;
}

__global__ void scatter_kernel(const int* __restrict__ ei, int* __restrict__ cur,
                               int* __restrict__ colb) {
  int e = blockIdx.x * blockDim.x + threadIdx.x;
  if (e >= TOT_E) return;
  int src, dst;
  if (e < E_EDGES) { src = ei[e]; dst = ei[E_EDGES + e]; }
  else             { src = dst = e - E_EDGES; }
  int pos = atomicAdd(&cur[dst], 1);
  colb[pos] = src;
}

// ---------- input conversions: W -> Wt bf16 transposed; x -> bf16 ----------
__global__ __launch_bounds__(256)
void conv_inputs_kernel(const float* __restrict__ W1, const float* __restrict__ W2,
                        const float* __restrict__ x, ushort* __restrict__ Wt1,
                        ushort* __restrict__ Wt2, ushort* __restrict__ xb) {
  const int b = blockIdx.x;
  if (b < 512) {
    const float* W = (b < 256) ? W1 : W2;
    ushort* Wt = (b < 256) ? Wt1 : Wt2;
    const int n = b & 255;
    const int k = threadIdx.x;
    Wt[n * 256 + k] = f2bf(W[k * 256 + n]);
  } else {
    int idx = (b - 512) * 256 + threadIdx.x;  // granule of 8
    size_t base = (size_t)idx * 8;
    float4 a = *reinterpret_cast<const float4*>(x + base);
    float4 c = *reinterpret_cast<const float4*>(x + base + 4);
    short8 o;
    o[0] = f2bf(a.x); o[1] = f2bf(a.y); o[2] = f2bf(a.z); o[3] = f2bf(a.w);
    o[4] = f2bf(c.x); o[5] = f2bf(c.y); o[6] = f2bf(c.z); o[7] = f2bf(c.w);
    *reinterpret_cast<short8*>(xb + base) = o;
  }
}

// ---------- bf16-MFMA GEMM (pipelined, barrier-free) + alpha epilogue ----------
// h[M,256] = bf16(Ab @ W); as_/ad_ per-row-head dots.
// Block: 32 rows x 256 cols, 4 waves; wave w = head/col-quarter.
__global__ __launch_bounds__(256)
void gemm_alpha_kernel(const ushort* __restrict__ Ab, const ushort* __restrict__ Wt,
                       const float* __restrict__ asrc, const float* __restrict__ adst,
                       ushort* __restrict__ hout, float* __restrict__ as_,
                       float* __restrict__ ad_) {
  __shared__ ushort hs[32 * 256];  // 16 KB repack buffer

  const int t = threadIdx.x;
  const int w = t >> 6;
  const int l = t & 63;
  const int row0 = blockIdx.x * 32;

  const ushort* abase = Ab + (size_t)(row0 + (l & 15)) * 256 + ((l >> 4) * 8);
  const ushort* bbase = Wt + (size_t)(w * 64 + (l & 15)) * 256 + ((l >> 4) * 8);

  f32x4 acc[2][4];
#pragma unroll
  for (int i = 0; i < 2; ++i)
#pragma unroll
    for (int j = 0; j < 4; ++j) acc[i][j] = (f32x4){0.f, 0.f, 0.f, 0.f};

  short8 a0 = *reinterpret_cast<const short8*>(abase);
  short8 a1 = *reinterpret_cast<const short8*>(abase + 16 * 256);
  short8 b0 = *reinterpret_cast<const short8*>(bbase);
  short8 b1 = *reinterpret_cast<const short8*>(bbase + 16 * 256);
  short8 b2 = *reinterpret_cast<const short8*>(bbase + 32 * 256);
  short8 b3 = *reinterpret_cast<const short8*>(bbase + 48 * 256);
#pragma unroll
  for (int kk = 0; kk < 256; kk += 32) {
    short8 na0, na1, nb0, nb1, nb2, nb3;
    if (kk + 32 < 256) {
      na0 = *reinterpret_cast<const short8*>(abase + kk + 32);
      na1 = *reinterpret_cast<const short8*>(abase + 16 * 256 + kk + 32);
      nb0 = *reinterpret_cast<const short8*>(bbase + kk + 32);
      nb1 = *reinterpret_cast<const short8*>(bbase + 16 * 256 + kk + 32);
      nb2 = *reinterpret_cast<const short8*>(bbase + 32 * 256 + kk + 32);
      nb3 = *reinterpret_cast<const short8*>(bbase + 48 * 256 + kk + 32);
    }
    acc[0][0] = __builtin_amdgcn_mfma_f32_16x16x32_bf16(a0, b0, acc[0][0], 0, 0, 0);
    acc[0][1] = __builtin_amdgcn_mfma_f32_16x16x32_bf16(a0, b1, acc[0][1], 0, 0, 0);
    acc[0][2] = __builtin_amdgcn_mfma_f32_16x16x32_bf16(a0, b2, acc[0][2], 0, 0, 0);
    acc[0][3] = __builtin_amdgcn_mfma_f32_16x16x32_bf16(a0, b3, acc[0][3], 0, 0, 0);
    acc[1][0] = __builtin_amdgcn_mfma_f32_16x16x32_bf16(a1, b0, acc[1][0], 0, 0, 0);
    acc[1][1] = __builtin_amdgcn_mfma_f32_16x16x32_bf16(a1, b1, acc[1][1], 0, 0, 0);
    acc[1][2] = __builtin_amdgcn_mfma_f32_16x16x32_bf16(a1, b2, acc[1][2], 0, 0, 0);
    acc[1][3] = __builtin_amdgcn_mfma_f32_16x16x32_bf16(a1, b3, acc[1][3], 0, 0, 0);
    if (kk + 32 < 256) {
      a0 = na0; a1 = na1; b0 = nb0; b1 = nb1; b2 = nb2; b3 = nb3;
    }
  }

  // ---- alpha epilogue: wave w owns head w, rows row0..row0+31 ----
  float asj[4], adj[4];
#pragma unroll
  for (int j = 0; j < 4; ++j) {
    asj[j] = asrc[w * 64 + j * 16 + (l & 15)];
    adj[j] = adst[w * 64 + j * 16 + (l & 15)];
  }
#pragma unroll
  for (int i = 0; i < 2; ++i) {
#pragma unroll
    for (int q = 0; q < 4; ++q) {
      float ps = 0.f, pd = 0.f;
#pragma unroll
      for (int j = 0; j < 4; ++j) {
        ps += acc[i][j][q] * asj[j];
        pd += acc[i][j][q] * adj[j];
      }
#pragma unroll
      for (int off = 1; off < 16; off <<= 1) {
        ps += __shfl_xor(ps, off);
        pd += __shfl_xor(pd, off);
      }
      int row = row0 + i * 16 + (l >> 4) * 4 + q;
      if ((l & 15) == 0) {
        as_[row * 4 + w] = ps;
        ad_[row * 4 + w] = pd;
      }
    }
  }

  // ---- h repack: fragments -> LDS bf16 -> coalesced global ----
#pragma unroll
  for (int i = 0; i < 2; ++i)
#pragma unroll
    for (int j = 0; j < 4; ++j)
#pragma unroll
      for (int q = 0; q < 4; ++q) {
        int row = i * 16 + (l >> 4) * 4 + q;
        int col = w * 64 + j * 16 + (l & 15);
        hs[row * 256 + col] = f2bf(acc[i][j][q]);
      }
  __syncthreads();
#pragma unroll
  for (int g = 0; g < 4; ++g) {
    int gi = g * 256 + t;
    int row = gi >> 5;
    int slot = gi & 31;
    *reinterpret_cast<short8*>(hout + (size_t)(row0 + row) * 256 + slot * 8) =
        *reinterpret_cast<const short8*>(&hs[row * 256 + slot * 8]);
  }
}

// ---------- per-dst attention weights: wave per dst, no LDS ----------
// wbuf[slot][h] = exp(e - M_dst,h); zinv[d][h] = 1/(sum + 1e-16)
__global__ __launch_bounds__(256)
void attn_w_kernel(const float* __restrict__ as_, const float* __restrict__ ad_,
                   const int* __restrict__ rowp, const int* __restrict__ colb,
                   float* __restrict__ wbuf, float* __restrict__ zinv) {
  const int t = threadIdx.x;
  const int d = blockIdx.x * 4 + (t >> 6);
  const int l = t & 63;
  const int e16 = l >> 2;   // edge residue 0..15
  const int hh = l & 3;     // head
  const int start = rowp[d];
  const int deg = rowp[d + 1] - start;
  const float adv = ad_[d * 4 + hh];

  float M = -INFINITY;
  for (int base = 0; base < deg; base += 16) {
    int i = base + e16;
    float ev = -INFINITY;
    if (i < deg) {
      int s = colb[start + i];
      float e = as_[s * 4 + hh] + adv;
      ev = (e >= 0.f) ? e : 0.2f * e;
    }
    M = fmaxf(M, ev);
  }
#pragma unroll
  for (int off = 4; off < 64; off <<= 1) M = fmaxf(M, __shfl_xor(M, off));

  float z = 0.f;
  for (int base = 0; base < deg; base += 16) {
    int i = base + e16;
    if (i < deg) {
      int s = colb[start + i];
      float e = as_[s * 4 + hh] + adv;
      e = (e >= 0.f) ? e : 0.2f * e;
      float wv = __expf(e - M);
      wbuf[(size_t)(start + i) * 4 + hh] = wv;
      z += wv;
    }
  }
#pragma unroll
  for (int off = 4; off < 64; off <<= 1) z += __shfl_xor(z, off);
  if (e16 == 0) zinv[d * 4 + hh] = 1.f / (z + 1e-16f);
}

// ---------- gather + bias + LayerNorm (+bf16 residual) + ELU (+score) ----
// Wave per dst (4 per block). Lane l owns channels l*4..l*4+3; head = l>>4.
__global__ __launch_bounds__(256)
void gather_ln_kernel(const ushort* __restrict__ h, const int* __restrict__ rowp,
                      const int* __restrict__ colb, const float* __restrict__ wbuf,
                      const float* __restrict__ zinv, const float* __restrict__ bias,
                      const float* __restrict__ gamma, const float* __restrict__ beta,
                      const ushort* __restrict__ residb, float* __restrict__ outf,
                      ushort* __restrict__ outb, const float* __restrict__ aw,
                      const float* __restrict__ ab, float* __restrict__ score) {
  const int t = threadIdx.x;
  const int d = blockIdx.x * 4 + (t >> 6);
  const int l = t & 63;
  const int hh = l >> 4;
  const int c0 = l * 4;
  const int start = rowp[d];
  const int deg = rowp[d + 1] - start;

  float a0 = 0.f, a1 = 0.f, a2 = 0.f, a3 = 0.f;
  const ushort* hrow = h + c0;
#pragma unroll 2
  for (int i = 0; i < deg; ++i) {
    const int slot = start + i;
    int s = colb[slot];
    float wv = wbuf[(size_t)slot * 4 + hh];
    uint2 hv = *reinterpret_cast<const uint2*>(hrow + (size_t)s * 256);
    a0 += wv * bflo(hv.x);
    a1 += wv * bfhi(hv.x);
    a2 += wv * bflo(hv.y);
    a3 += wv * bfhi(hv.y);
  }
  const float zi = zinv[d * 4 + hh];
  float4 bi = *reinterpret_cast<const float4*>(bias + c0);
  float v0 = a0 * zi + bi.x, v1 = a1 * zi + bi.y;
  float v2 = a2 * zi + bi.z, v3 = a3 * zi + bi.w;

  float s1 = wave_sum(v0 + v1 + v2 + v3);
  float s2 = wave_sum(v0 * v0 + v1 * v1 + v2 * v2 + v3 * v3);
  float mu = s1 * (1.f / 256.f);
  float var = s2 * (1.f / 256.f) - mu * mu;
  float rstd = rsqrtf(var + 1e-5f);
  float4 ga = *reinterpret_cast<const float4*>(gamma + c0);
  float4 be = *reinterpret_cast<const float4*>(beta + c0);
  float y0 = (v0 - mu) * rstd * ga.x + be.x;
  float y1 = (v1 - mu) * rstd * ga.y + be.y;
  float y2 = (v2 - mu) * rstd * ga.z + be.z;
  float y3 = (v3 - mu) * rstd * ga.w + be.w;
  if (residb) {
    uint2 rv = *reinterpret_cast<const uint2*>(residb + (size_t)d * 256 + c0);
    y0 += bflo(rv.x); y1 += bfhi(rv.x); y2 += bflo(rv.y); y3 += bfhi(rv.y);
  }
  y0 = (y0 > 0.f) ? y0 : expm1f(y0);
  y1 = (y1 > 0.f) ? y1 : expm1f(y1);
  y2 = (y2 > 0.f) ? y2 : expm1f(y2);
  y3 = (y3 > 0.f) ? y3 : expm1f(y3);

  if (outb) {
    uint2 o;
    o.x = ((unsigned)f2bf(y0)) | (((unsigned)f2bf(y1)) << 16);
    o.y = ((unsigned)f2bf(y2)) | (((unsigned)f2bf(y3)) << 16);
    *reinterpret_cast<uint2*>(outb + (size_t)d * 256 + c0) = o;
  }
  if (outf) {
    *reinterpret_cast<float4*>(outf + (size_t)d * 256 + c0) =
        make_float4(y0, y1, y2, y3);
  }
  if (score) {
    float4 aww = *reinterpret_cast<const float4*>(aw + c0);
    float sp = wave_sum(y0 * aww.x + y1 * aww.y + y2 * aww.z + y3 * aww.w);
    if (l == 0) score[d] = sp + ab[0];
  }
}

// ---------- pooling ----------
__global__ __launch_bounds__(256)
void softmax_reduce_kernel(const float* __restrict__ s, float* __restrict__ mz) {
  __shared__ float red[4];
  const int t = threadIdx.x, lane = t & 63, wid = t >> 6;
  float m = -INFINITY;
  for (int n4 = t; n4 < N_NODES / 4; n4 += 256) {
    float4 v = *reinterpret_cast<const float4*>(s + n4 * 4);
    m = fmaxf(m, fmaxf(fmaxf(v.x, v.y), fmaxf(v.z, v.w)));
  }
#pragma unroll
  for (int off = 32; off; off >>= 1) m = fmaxf(m, __shfl_xor(m, off));
  if (lane == 0) red[wid] = m;
  __syncthreads();
  m = fmaxf(fmaxf(red[0], red[1]), fmaxf(red[2], red[3]));
  __syncthreads();
  float z = 0.f;
  for (int n4 = t; n4 < N_NODES / 4; n4 += 256) {
    float4 v = *reinterpret_cast<const float4*>(s + n4 * 4);
    z += __expf(v.x - m) + __expf(v.y - m) + __expf(v.z - m) + __expf(v.w - m);
  }
  z = wave_sum(z);
  if (lane == 0) red[wid] = z;
  __syncthreads();
  if (t == 0) { mz[0] = m; mz[1] = red[0] + red[1] + red[2] + red[3]; }
}

__global__ __launch_bounds__(256)
void pool_partial_kernel(const float* __restrict__ x2, const float* __restrict__ s,
                         const float* __restrict__ mz, float* __restrict__ part) {
  __shared__ float red4[4][256];
  const int t = threadIdx.x, b = blockIdx.x;
  const int c4 = t & 63, rsub = t >> 6;
  const float m = mz[0];
  const float invz = 1.f / mz[1];
  f32x4 acc = (f32x4){0.f, 0.f, 0.f, 0.f};
  for (int n = b * 4 + rsub; n < N_NODES; n += 1024) {
    float w = __expf(s[n] - m);
    float4 xv = *reinterpret_cast<const float4*>(&x2[(size_t)n * 256 + c4 * 4]);
    acc[0] += w * xv.x; acc[1] += w * xv.y; acc[2] += w * xv.z; acc[3] += w * xv.w;
  }
#pragma unroll
  for (int k = 0; k < 4; ++k) red4[rsub][c4 * 4 + k] = acc[k];
  __syncthreads();
  if (t < 256) {
    float v = red4[0][t] + red4[1][t] + red4[2][t] + red4[3][t];
    part[b * 256 + t] = v * invz;
  }
}

__global__ __launch_bounds__(256)
void pool_final_kernel(const float* __restrict__ part, float* __restrict__ out) {
  const int t = threadIdx.x;
  float acc = 0.f;
  for (int b = 0; b < 256; ++b) acc += part[b * 256 + t];
  out[t] = acc;
}

extern "C" void kernel_launch(void* const* d_in, const int* in_sizes, int n_in,
                              void* d_out, int out_size, void* d_ws, size_t ws_size,
                              hipStream_t stream) {
  const float* x      = (const float*)d_in[0];
  const int*   ei     = (const int*)d_in[1];
  const float* W1     = (const float*)d_in[2];
  const float* b1     = (const float*)d_in[3];
  const float* a_src1 = (const float*)d_in[4];
  const float* a_dst1 = (const float*)d_in[5];
  const float* W2     = (const float*)d_in[6];
  const float* b2     = (const float*)d_in[7];
  const float* a_src2 = (const float*)d_in[8];
  const float* a_dst2 = (const float*)d_in[9];
  const float* g1     = (const float*)d_in[10];
  const float* be1    = (const float*)d_in[11];
  const float* g2     = (const float*)d_in[12];
  const float* be2    = (const float*)d_in[13];
  const float* attn_w = (const float*)d_in[14];
  const float* attn_b = (const float*)d_in[15];
  float* out = (float*)d_out;

  char* p = (char*)d_ws;
  auto alloc = [&](size_t bytes) {
    char* r = p;
    p += (bytes + 255) & ~size_t(255);
    return r;
  };
  ushort* h   = (ushort*)alloc((size_t)N_NODES * 256 * 2);
  ushort* xb  = (ushort*)alloc((size_t)N_NODES * 256 * 2);
  ushort* xb1 = (ushort*)alloc((size_t)N_NODES * 256 * 2);
  float* x2   = (float*)alloc((size_t)N_NODES * 256 * 4);
  float* as_  = (float*)alloc((size_t)N_NODES * 4 * 4);
  float* ad_  = (float*)alloc((size_t)N_NODES * 4 * 4);
  float* zinv = (float*)alloc((size_t)N_NODES * 4 * 4);
  float* wbuf = (float*)alloc((size_t)TOT_E * 4 * 4);
  float* sbuf = (float*)alloc((size_t)N_NODES * 4);
  float* mz   = (float*)alloc(256);
  float* part = (float*)alloc((size_t)256 * 256 * 4);
  ushort* wt1 = (ushort*)alloc((size_t)256 * 256 * 2);
  ushort* wt2 = (ushort*)alloc((size_t)256 * 256 * 2);
  int* deg    = (int*)alloc((size_t)N_NODES * 4);
  int* rowp   = (int*)alloc((size_t)(N_NODES + 1) * 4);
  int* cur    = (int*)alloc((size_t)N_NODES * 4);
  int* colb   = (int*)alloc((size_t)TOT_E * 4);

  const int EB = (TOT_E + 255) / 256;
  const int GB = N_NODES / 32;   // 625
  const int DB = N_NODES / 4;    // 5000 (4 dst-waves per block)

  hipMemsetAsync(deg, 0, (size_t)N_NODES * 4, stream);
  hist_kernel<<<EB, 256, 0, stream>>>(ei, deg);
  conv_inputs_kernel<<<512 + N_NODES * 256 / 8 / 256, 256, 0, stream>>>(
      W1, W2, x, wt1, wt2, xb);
  scan_kernel<<<1, 256, 0, stream>>>(deg, rowp, cur);
  scatter_kernel<<<EB, 256, 0, stream>>>(ei, cur, colb);

  // layer 1: out = bf16 xb1 (residual + layer-2 A)
  gemm_alpha_kernel<<<GB, 256, 0, stream>>>(xb, wt1, a_src1, a_dst1, h, as_, ad_);
  attn_w_kernel<<<DB, 256, 0, stream>>>(as_, ad_, rowp, colb, wbuf, zinv);
  gather_ln_kernel<<<DB, 256, 0, stream>>>(h, rowp, colb, wbuf, zinv, b1, g1, be1,
                                           nullptr, nullptr, xb1,
                                           nullptr, nullptr, nullptr);
  // layer 2: out = f32 x2 + fused score
  gemm_alpha_kernel<<<GB, 256, 0, stream>>>(xb1, wt2, a_src2, a_dst2, h, as_, ad_);
  attn_w_kernel<<<DB, 256, 0, stream>>>(as_, ad_, rowp, colb, wbuf, zinv);
  gather_ln_kernel<<<DB, 256, 0, stream>>>(h, rowp, colb, wbuf, zinv, b2, g2, be2,
                                           xb1, x2, nullptr,
                                           attn_w, attn_b, sbuf);
  // pooling
  softmax_reduce_kernel<<<1, 256, 0, stream>>>(sbuf, mz);
  pool_partial_kernel<<<256, 256, 0, stream>>>(x2, sbuf, mz, part);
  pool_final_kernel<<<1, 256, 0, stream>>>(part, out);
}

// Round 6
// 214.628 us; speedup vs baseline: 2.1964x; 1.1863x over previous
//
#include <hip/hip_runtime.h>
#include <math.h>

#define N_NODES 20000
#define E_EDGES 320000
#define TOT_E   (E_EDGES + N_NODES)
#define DHID    256
#define NHEAD   4
#define SCAN_NB ((N_NODES + 255) / 256)   // 79

typedef float f32x4 __attribute__((ext_vector_type(4)));
typedef short short8 __attribute__((ext_vector_type(8)));
typedef unsigned short ushort;

// ---------- helpers ----------
__device__ __forceinline__ float wave_sum(float v) {
#pragma unroll
  for (int off = 32; off; off >>= 1) v += __shfl_xor(v, off);
  return v;
}
__device__ __forceinline__ ushort f2bf(float f) {  // RNE f32 -> bf16
  unsigned u = __float_as_uint(f);
  u += 0x7fffu + ((u >> 16) & 1u);
  return (ushort)(u >> 16);
}
__device__ __forceinline__ float bflo(unsigned u) {
  return __uint_as_float(u << 16);
}
__device__ __forceinline__ float bfhi(unsigned u) {
  return __uint_as_float(u & 0xffff0000u);
}

// ---------- CSR build ----------
__global__ void hist_kernel(const int* __restrict__ ei, int* __restrict__ deg) {
  int e = blockIdx.x * blockDim.x + threadIdx.x;
  if (e >= TOT_E) return;
  int dst = (e < E_EDGES) ? ei[E_EDGES + e] : (e - E_EDGES);
  atomicAdd(&deg[dst], 1);
}

// phase A: per-block sums
__global__ __launch_bounds__(256)
void scan_blocks_kernel(const int* __restrict__ deg, int* __restrict__ bsum) {
  __shared__ int ws[4];
  const int t = threadIdx.x;
  const int i = blockIdx.x * 256 + t;
  int v = (i < N_NODES) ? deg[i] : 0;
  int s = v;
#pragma unroll
  for (int off = 32; off; off >>= 1) s += __shfl_xor(s, off);
  if ((t & 63) == 0) ws[t >> 6] = s;
  __syncthreads();
  if (t == 0) bsum[blockIdx.x] = ws[0] + ws[1] + ws[2] + ws[3];
}

// phase B: exclusive scan of 79 block sums (tiny, LDS-serial)
__global__ __launch_bounds__(128)
void scan_tops_kernel(const int* __restrict__ bsum, int* __restrict__ boff) {
  __shared__ int tmp[SCAN_NB];
  const int t = threadIdx.x;
  if (t < SCAN_NB) tmp[t] = bsum[t];
  __syncthreads();
  if (t == 0) {
    int run = 0;
    for (int i = 0; i < SCAN_NB; ++i) { int x = tmp[i]; tmp[i] = run; run += x; }
  }
  __syncthreads();
  if (t < SCAN_NB) boff[t] = tmp[t];
}

// phase C: intra-block shuffle scan + offset -> rowp/cur
__global__ __launch_bounds__(256)
void scan_apply_kernel(const int* __restrict__ deg, const int* __restrict__ boff,
                       int* __restrict__ rowp, int* __restrict__ cur) {
  __shared__ int ws[4];
  const int t = threadIdx.x;
  const int lane = t & 63, w = t >> 6;
  const int i = blockIdx.x * 256 + t;
  int v = (i < N_NODES) ? deg[i] : 0;
  int inc = v;
#pragma unroll
  for (int off = 1; off < 64; off <<= 1) {
    int u = __shfl_up(inc, off);
    if (lane >= off) inc += u;
  }
  if (lane == 63) ws[w] = inc;
  __syncthreads();
  int add = boff[blockIdx.x];
#pragma unroll
  for (int k = 0; k < 4; ++k)
    if (k < w) add += ws[k];
  int exc = add + inc - v;
  if (i < N_NODES) {
    rowp[i] = exc;
    cur[i] = exc;
    if (i == N_NODES - 1) rowp[N_NODES] = exc + v;
  }
}

__global__ void scatter_kernel(const int* __restrict__ ei, int* __restrict__ cur,
                               int* __restrict__ colb) {
  int e = blockIdx.x * blockDim.x + threadIdx.x;
  if (e >= TOT_E) return;
  int src, dst;
  if (e < E_EDGES) { src = ei[e]; dst = ei[E_EDGES + e]; }
  else             { src = dst = e - E_EDGES; }
  int pos = atomicAdd(&cur[dst], 1);
  colb[pos] = src;
}

// ---------- input conversions: W -> Wt bf16 transposed; x -> bf16 ----------
__global__ __launch_bounds__(256)
void conv_inputs_kernel(const float* __restrict__ W1, const float* __restrict__ W2,
                        const float* __restrict__ x, ushort* __restrict__ Wt1,
                        ushort* __restrict__ Wt2, ushort* __restrict__ xb) {
  const int b = blockIdx.x;
  if (b < 512) {
    const float* W = (b < 256) ? W1 : W2;
    ushort* Wt = (b < 256) ? Wt1 : Wt2;
    const int n = b & 255;
    const int k = threadIdx.x;
    Wt[n * 256 + k] = f2bf(W[k * 256 + n]);
  } else {
    int idx = (b - 512) * 256 + threadIdx.x;  // granule of 8
    size_t base = (size_t)idx * 8;
    float4 a = *reinterpret_cast<const float4*>(x + base);
    float4 c = *reinterpret_cast<const float4*>(x + base + 4);
    short8 o;
    o[0] = f2bf(a.x); o[1] = f2bf(a.y); o[2] = f2bf(a.z); o[3] = f2bf(a.w);
    o[4] = f2bf(c.x); o[5] = f2bf(c.y); o[6] = f2bf(c.z); o[7] = f2bf(c.w);
    *reinterpret_cast<short8*>(xb + base) = o;
  }
}

// ---------- bf16-MFMA GEMM (pipelined, barrier-free) + alpha epilogue ----------
__global__ __launch_bounds__(256)
void gemm_alpha_kernel(const ushort* __restrict__ Ab, const ushort* __restrict__ Wt,
                       const float* __restrict__ asrc, const float* __restrict__ adst,
                       ushort* __restrict__ hout, float* __restrict__ as_,
                       float* __restrict__ ad_) {
  __shared__ ushort hs[32 * 256];  // 16 KB repack buffer

  const int t = threadIdx.x;
  const int w = t >> 6;
  const int l = t & 63;
  const int row0 = blockIdx.x * 32;

  const ushort* abase = Ab + (size_t)(row0 + (l & 15)) * 256 + ((l >> 4) * 8);
  const ushort* bbase = Wt + (size_t)(w * 64 + (l & 15)) * 256 + ((l >> 4) * 8);

  f32x4 acc[2][4];
#pragma unroll
  for (int i = 0; i < 2; ++i)
#pragma unroll
    for (int j = 0; j < 4; ++j) acc[i][j] = (f32x4){0.f, 0.f, 0.f, 0.f};

  short8 a0 = *reinterpret_cast<const short8*>(abase);
  short8 a1 = *reinterpret_cast<const short8*>(abase + 16 * 256);
  short8 b0 = *reinterpret_cast<const short8*>(bbase);
  short8 b1 = *reinterpret_cast<const short8*>(bbase + 16 * 256);
  short8 b2 = *reinterpret_cast<const short8*>(bbase + 32 * 256);
  short8 b3 = *reinterpret_cast<const short8*>(bbase + 48 * 256);
#pragma unroll
  for (int kk = 0; kk < 256; kk += 32) {
    short8 na0, na1, nb0, nb1, nb2, nb3;
    if (kk + 32 < 256) {
      na0 = *reinterpret_cast<const short8*>(abase + kk + 32);
      na1 = *reinterpret_cast<const short8*>(abase + 16 * 256 + kk + 32);
      nb0 = *reinterpret_cast<const short8*>(bbase + kk + 32);
      nb1 = *reinterpret_cast<const short8*>(bbase + 16 * 256 + kk + 32);
      nb2 = *reinterpret_cast<const short8*>(bbase + 32 * 256 + kk + 32);
      nb3 = *reinterpret_cast<const short8*>(bbase + 48 * 256 + kk + 32);
    }
    acc[0][0] = __builtin_amdgcn_mfma_f32_16x16x32_bf16(a0, b0, acc[0][0], 0, 0, 0);
    acc[0][1] = __builtin_amdgcn_mfma_f32_16x16x32_bf16(a0, b1, acc[0][1], 0, 0, 0);
    acc[0][2] = __builtin_amdgcn_mfma_f32_16x16x32_bf16(a0, b2, acc[0][2], 0, 0, 0);
    acc[0][3] = __builtin_amdgcn_mfma_f32_16x16x32_bf16(a0, b3, acc[0][3], 0, 0, 0);
    acc[1][0] = __builtin_amdgcn_mfma_f32_16x16x32_bf16(a1, b0, acc[1][0], 0, 0, 0);
    acc[1][1] = __builtin_amdgcn_mfma_f32_16x16x32_bf16(a1, b1, acc[1][1], 0, 0, 0);
    acc[1][2] = __builtin_amdgcn_mfma_f32_16x16x32_bf16(a1, b2, acc[1][2], 0, 0, 0);
    acc[1][3] = __builtin_amdgcn_mfma_f32_16x16x32_bf16(a1, b3, acc[1][3], 0, 0, 0);
    if (kk + 32 < 256) {
      a0 = na0; a1 = na1; b0 = nb0; b1 = nb1; b2 = nb2; b3 = nb3;
    }
  }

  // ---- alpha epilogue ----
  float asj[4], adj[4];
#pragma unroll
  for (int j = 0; j < 4; ++j) {
    asj[j] = asrc[w * 64 + j * 16 + (l & 15)];
    adj[j] = adst[w * 64 + j * 16 + (l & 15)];
  }
#pragma unroll
  for (int i = 0; i < 2; ++i) {
#pragma unroll
    for (int q = 0; q < 4; ++q) {
      float ps = 0.f, pd = 0.f;
#pragma unroll
      for (int j = 0; j < 4; ++j) {
        ps += acc[i][j][q] * asj[j];
        pd += acc[i][j][q] * adj[j];
      }
#pragma unroll
      for (int off = 1; off < 16; off <<= 1) {
        ps += __shfl_xor(ps, off);
        pd += __shfl_xor(pd, off);
      }
      int row = row0 + i * 16 + (l >> 4) * 4 + q;
      if ((l & 15) == 0) {
        as_[row * 4 + w] = ps;
        ad_[row * 4 + w] = pd;
      }
    }
  }

  // ---- h repack: fragments -> LDS bf16 -> coalesced global ----
#pragma unroll
  for (int i = 0; i < 2; ++i)
#pragma unroll
    for (int j = 0; j < 4; ++j)
#pragma unroll
      for (int q = 0; q < 4; ++q) {
        int row = i * 16 + (l >> 4) * 4 + q;
        int col = w * 64 + j * 16 + (l & 15);
        hs[row * 256 + col] = f2bf(acc[i][j][q]);
      }
  __syncthreads();
#pragma unroll
  for (int g = 0; g < 4; ++g) {
    int gi = g * 256 + t;
    int row = gi >> 5;
    int slot = gi & 31;
    *reinterpret_cast<short8*>(hout + (size_t)(row0 + row) * 256 + slot * 8) =
        *reinterpret_cast<const short8*>(&hs[row * 256 + slot * 8]);
  }
}

// ---------- per-dst attention weights: wave per dst, no LDS ----------
__global__ __launch_bounds__(256)
void attn_w_kernel(const float* __restrict__ as_, const float* __restrict__ ad_,
                   const int* __restrict__ rowp, const int* __restrict__ colb,
                   float* __restrict__ wbuf, float* __restrict__ zinv) {
  const int t = threadIdx.x;
  const int d = blockIdx.x * 4 + (t >> 6);
  const int l = t & 63;
  const int e16 = l >> 2;   // edge residue 0..15
  const int hh = l & 3;     // head
  const int start = rowp[d];
  const int deg = rowp[d + 1] - start;
  const float adv = ad_[d * 4 + hh];

  float M = -INFINITY;
  for (int base = 0; base < deg; base += 16) {
    int i = base + e16;
    float ev = -INFINITY;
    if (i < deg) {
      int s = colb[start + i];
      float e = as_[s * 4 + hh] + adv;
      ev = (e >= 0.f) ? e : 0.2f * e;
    }
    M = fmaxf(M, ev);
  }
#pragma unroll
  for (int off = 4; off < 64; off <<= 1) M = fmaxf(M, __shfl_xor(M, off));

  float z = 0.f;
  for (int base = 0; base < deg; base += 16) {
    int i = base + e16;
    if (i < deg) {
      int s = colb[start + i];
      float e = as_[s * 4 + hh] + adv;
      e = (e >= 0.f) ? e : 0.2f * e;
      float wv = __expf(e - M);
      wbuf[(size_t)(start + i) * 4 + hh] = wv;
      z += wv;
    }
  }
#pragma unroll
  for (int off = 4; off < 64; off <<= 1) z += __shfl_xor(z, off);
  if (e16 == 0) zinv[d * 4 + hh] = 1.f / (z + 1e-16f);
}

// ---------- gather + bias + LayerNorm (+bf16 residual) + ELU (+score) ----
__global__ __launch_bounds__(256)
void gather_ln_kernel(const ushort* __restrict__ h, const int* __restrict__ rowp,
                      const int* __restrict__ colb, const float* __restrict__ wbuf,
                      const float* __restrict__ zinv, const float* __restrict__ bias,
                      const float* __restrict__ gamma, const float* __restrict__ beta,
                      const ushort* __restrict__ residb, float* __restrict__ outf,
                      ushort* __restrict__ outb, const float* __restrict__ aw,
                      const float* __restrict__ ab, float* __restrict__ score) {
  const int t = threadIdx.x;
  const int d = blockIdx.x * 4 + (t >> 6);
  const int l = t & 63;
  const int hh = l >> 4;
  const int c0 = l * 4;
  const int start = rowp[d];
  const int deg = rowp[d + 1] - start;

  float a0 = 0.f, a1 = 0.f, a2 = 0.f, a3 = 0.f;
  const ushort* hrow = h + c0;
#pragma unroll 2
  for (int i = 0; i < deg; ++i) {
    const int slot = start + i;
    int s = colb[slot];
    float wv = wbuf[(size_t)slot * 4 + hh];
    uint2 hv = *reinterpret_cast<const uint2*>(hrow + (size_t)s * 256);
    a0 += wv * bflo(hv.x);
    a1 += wv * bfhi(hv.x);
    a2 += wv * bflo(hv.y);
    a3 += wv * bfhi(hv.y);
  }
  const float zi = zinv[d * 4 + hh];
  float4 bi = *reinterpret_cast<const float4*>(bias + c0);
  float v0 = a0 * zi + bi.x, v1 = a1 * zi + bi.y;
  float v2 = a2 * zi + bi.z, v3 = a3 * zi + bi.w;

  float s1 = wave_sum(v0 + v1 + v2 + v3);
  float s2 = wave_sum(v0 * v0 + v1 * v1 + v2 * v2 + v3 * v3);
  float mu = s1 * (1.f / 256.f);
  float var = s2 * (1.f / 256.f) - mu * mu;
  float rstd = rsqrtf(var + 1e-5f);
  float4 ga = *reinterpret_cast<const float4*>(gamma + c0);
  float4 be = *reinterpret_cast<const float4*>(beta + c0);
  float y0 = (v0 - mu) * rstd * ga.x + be.x;
  float y1 = (v1 - mu) * rstd * ga.y + be.y;
  float y2 = (v2 - mu) * rstd * ga.z + be.z;
  float y3 = (v3 - mu) * rstd * ga.w + be.w;
  if (residb) {
    uint2 rv = *reinterpret_cast<const uint2*>(residb + (size_t)d * 256 + c0);
    y0 += bflo(rv.x); y1 += bfhi(rv.x); y2 += bflo(rv.y); y3 += bfhi(rv.y);
  }
  y0 = (y0 > 0.f) ? y0 : expm1f(y0);
  y1 = (y1 > 0.f) ? y1 : expm1f(y1);
  y2 = (y2 > 0.f) ? y2 : expm1f(y2);
  y3 = (y3 > 0.f) ? y3 : expm1f(y3);

  if (outb) {
    uint2 o;
    o.x = ((unsigned)f2bf(y0)) | (((unsigned)f2bf(y1)) << 16);
    o.y = ((unsigned)f2bf(y2)) | (((unsigned)f2bf(y3)) << 16);
    *reinterpret_cast<uint2*>(outb + (size_t)d * 256 + c0) = o;
  }
  if (outf) {
    *reinterpret_cast<float4*>(outf + (size_t)d * 256 + c0) =
        make_float4(y0, y1, y2, y3);
  }
  if (score) {
    float4 aww = *reinterpret_cast<const float4*>(aw + c0);
    float sp = wave_sum(y0 * aww.x + y1 * aww.y + y2 * aww.z + y3 * aww.w);
    if (l == 0) score[d] = sp + ab[0];
  }
}

// ---------- pooling ----------
__global__ __launch_bounds__(256)
void softmax_reduce_kernel(const float* __restrict__ s, float* __restrict__ mz) {
  __shared__ float red[4];
  const int t = threadIdx.x, lane = t & 63, wid = t >> 6;
  float m = -INFINITY;
  for (int n4 = t; n4 < N_NODES / 4; n4 += 256) {
    float4 v = *reinterpret_cast<const float4*>(s + n4 * 4);
    m = fmaxf(m, fmaxf(fmaxf(v.x, v.y), fmaxf(v.z, v.w)));
  }
#pragma unroll
  for (int off = 32; off; off >>= 1) m = fmaxf(m, __shfl_xor(m, off));
  if (lane == 0) red[wid] = m;
  __syncthreads();
  m = fmaxf(fmaxf(red[0], red[1]), fmaxf(red[2], red[3]));
  __syncthreads();
  float z = 0.f;
  for (int n4 = t; n4 < N_NODES / 4; n4 += 256) {
    float4 v = *reinterpret_cast<const float4*>(s + n4 * 4);
    z += __expf(v.x - m) + __expf(v.y - m) + __expf(v.z - m) + __expf(v.w - m);
  }
  z = wave_sum(z);
  if (lane == 0) red[wid] = z;
  __syncthreads();
  if (t == 0) { mz[0] = m; mz[1] = red[0] + red[1] + red[2] + red[3]; }
}

__global__ __launch_bounds__(256)
void pool_partial_kernel(const float* __restrict__ x2, const float* __restrict__ s,
                         const float* __restrict__ mz, float* __restrict__ part) {
  __shared__ float red4[4][256];
  const int t = threadIdx.x, b = blockIdx.x;
  const int c4 = t & 63, rsub = t >> 6;
  const float m = mz[0];
  const float invz = 1.f / mz[1];
  f32x4 acc = (f32x4){0.f, 0.f, 0.f, 0.f};
  for (int n = b * 4 + rsub; n < N_NODES; n += 1024) {
    float w = __expf(s[n] - m);
    float4 xv = *reinterpret_cast<const float4*>(&x2[(size_t)n * 256 + c4 * 4]);
    acc[0] += w * xv.x; acc[1] += w * xv.y; acc[2] += w * xv.z; acc[3] += w * xv.w;
  }
#pragma unroll
  for (int k = 0; k < 4; ++k) red4[rsub][c4 * 4 + k] = acc[k];
  __syncthreads();
  if (t < 256) {
    float v = red4[0][t] + red4[1][t] + red4[2][t] + red4[3][t];
    part[b * 256 + t] = v * invz;
  }
}

__global__ __launch_bounds__(256)
void pool_final_kernel(const float* __restrict__ part, float* __restrict__ out) {
  const int t = threadIdx.x;
  float acc = 0.f;
  for (int b = 0; b < 256; ++b) acc += part[b * 256 + t];
  out[t] = acc;
}

extern "C" void kernel_launch(void* const* d_in, const int* in_sizes, int n_in,
                              void* d_out, int out_size, void* d_ws, size_t ws_size,
                              hipStream_t stream) {
  const float* x      = (const float*)d_in[0];
  const int*   ei     = (const int*)d_in[1];
  const float* W1     = (const float*)d_in[2];
  const float* b1     = (const float*)d_in[3];
  const float* a_src1 = (const float*)d_in[4];
  const float* a_dst1 = (const float*)d_in[5];
  const float* W2     = (const float*)d_in[6];
  const float* b2     = (const float*)d_in[7];
  const float* a_src2 = (const float*)d_in[8];
  const float* a_dst2 = (const float*)d_in[9];
  const float* g1     = (const float*)d_in[10];
  const float* be1    = (const float*)d_in[11];
  const float* g2     = (const float*)d_in[12];
  const float* be2    = (const float*)d_in[13];
  const float* attn_w = (const float*)d_in[14];
  const float* attn_b = (const float*)d_in[15];
  float* out = (float*)d_out;

  char* p = (char*)d_ws;
  auto alloc = [&](size_t bytes) {
    char* r = p;
    p += (bytes + 255) & ~size_t(255);
    return r;
  };
  ushort* h   = (ushort*)alloc((size_t)N_NODES * 256 * 2);
  ushort* xb  = (ushort*)alloc((size_t)N_NODES * 256 * 2);
  ushort* xb1 = (ushort*)alloc((size_t)N_NODES * 256 * 2);
  float* x2   = (float*)alloc((size_t)N_NODES * 256 * 4);
  float* as_  = (float*)alloc((size_t)N_NODES * 4 * 4);
  float* ad_  = (float*)alloc((size_t)N_NODES * 4 * 4);
  float* zinv = (float*)alloc((size_t)N_NODES * 4 * 4);
  float* wbuf = (float*)alloc((size_t)TOT_E * 4 * 4);
  float* sbuf = (float*)alloc((size_t)N_NODES * 4);
  float* mz   = (float*)alloc(256);
  float* part = (float*)alloc((size_t)256 * 256 * 4);
  ushort* wt1 = (ushort*)alloc((size_t)256 * 256 * 2);
  ushort* wt2 = (ushort*)alloc((size_t)256 * 256 * 2);
  int* deg    = (int*)alloc((size_t)N_NODES * 4);
  int* rowp   = (int*)alloc((size_t)(N_NODES + 1) * 4);
  int* cur    = (int*)alloc((size_t)N_NODES * 4);
  int* colb   = (int*)alloc((size_t)TOT_E * 4);
  int* bsum   = (int*)alloc((size_t)SCAN_NB * 4);
  int* boff   = (int*)alloc((size_t)SCAN_NB * 4);

  const int EB = (TOT_E + 255) / 256;
  const int GB = N_NODES / 32;   // 625
  const int DB = N_NODES / 4;    // 5000 (4 dst-waves per block)

  hipMemsetAsync(deg, 0, (size_t)N_NODES * 4, stream);
  hist_kernel<<<EB, 256, 0, stream>>>(ei, deg);
  conv_inputs_kernel<<<512 + N_NODES * 256 / 8 / 256, 256, 0, stream>>>(
      W1, W2, x, wt1, wt2, xb);
  scan_blocks_kernel<<<SCAN_NB, 256, 0, stream>>>(deg, bsum);
  scan_tops_kernel<<<1, 128, 0, stream>>>(bsum, boff);
  scan_apply_kernel<<<SCAN_NB, 256, 0, stream>>>(deg, boff, rowp, cur);
  scatter_kernel<<<EB, 256, 0, stream>>>(ei, cur, colb);

  // layer 1: out = bf16 xb1 (residual + layer-2 A)
  gemm_alpha_kernel<<<GB, 256, 0, stream>>>(xb, wt1, a_src1, a_dst1, h, as_, ad_);
  attn_w_kernel<<<DB, 256, 0, stream>>>(as_, ad_, rowp, colb, wbuf, zinv);
  gather_ln_kernel<<<DB, 256, 0, stream>>>(h, rowp, colb, wbuf, zinv, b1, g1, be1,
                                           nullptr, nullptr, xb1,
                                           nullptr, nullptr, nullptr);
  // layer 2: out = f32 x2 + fused score
  gemm_alpha_kernel<<<GB, 256, 0, stream>>>(xb1, wt2, a_src2, a_dst2, h, as_, ad_);
  attn_w_kernel<<<DB, 256, 0, stream>>>(as_, ad_, rowp, colb, wbuf, zinv);
  gather_ln_kernel<<<DB, 256, 0, stream>>>(h, rowp, colb, wbuf, zinv, b2, g2, be2,
                                           xb1, x2, nullptr,
                                           attn_w, attn_b, sbuf);
  // pooling
  softmax_reduce_kernel<<<1, 256, 0, stream>>>(sbuf, mz);
  pool_partial_kernel<<<256, 256, 0, stream>>>(x2, sbuf, mz, part);
  pool_final_kernel<<<1, 256, 0, stream>>>(part, out);
}

// Round 7
// 193.992 us; speedup vs baseline: 2.4300x; 1.1064x over previous
//
#include <hip/hip_runtime.h>
#include <math.h>

#define N_NODES 20000
#define E_EDGES 320000
#define TOT_E   (E_EDGES + N_NODES)
#define DHID    256
#define NHEAD   4
#define SCAN_NB ((N_NODES + 255) / 256)   // 79
#define SPART   32

typedef float f32x4 __attribute__((ext_vector_type(4)));
typedef short short8 __attribute__((ext_vector_type(8)));
typedef unsigned short ushort;

// ---------- helpers ----------
__device__ __forceinline__ float wave_sum(float v) {
#pragma unroll
  for (int off = 32; off; off >>= 1) v += __shfl_xor(v, off);
  return v;
}
__device__ __forceinline__ ushort f2bf(float f) {  // RNE f32 -> bf16
  unsigned u = __float_as_uint(f);
  u += 0x7fffu + ((u >> 16) & 1u);
  return (ushort)(u >> 16);
}
__device__ __forceinline__ float bflo(unsigned u) {
  return __uint_as_float(u << 16);
}
__device__ __forceinline__ float bfhi(unsigned u) {
  return __uint_as_float(u & 0xffff0000u);
}

// ---------- CSR build ----------
__global__ void hist_kernel(const int* __restrict__ ei, int* __restrict__ deg) {
  int e = blockIdx.x * blockDim.x + threadIdx.x;
  if (e >= TOT_E) return;
  int dst = (e < E_EDGES) ? ei[E_EDGES + e] : (e - E_EDGES);
  atomicAdd(&deg[dst], 1);
}

__global__ __launch_bounds__(256)
void scan_blocks_kernel(const int* __restrict__ deg, int* __restrict__ bsum) {
  __shared__ int ws[4];
  const int t = threadIdx.x;
  const int i = blockIdx.x * 256 + t;
  int v = (i < N_NODES) ? deg[i] : 0;
  int s = v;
#pragma unroll
  for (int off = 32; off; off >>= 1) s += __shfl_xor(s, off);
  if ((t & 63) == 0) ws[t >> 6] = s;
  __syncthreads();
  if (t == 0) bsum[blockIdx.x] = ws[0] + ws[1] + ws[2] + ws[3];
}

__global__ __launch_bounds__(128)
void scan_tops_kernel(const int* __restrict__ bsum, int* __restrict__ boff) {
  __shared__ int tmp[SCAN_NB];
  const int t = threadIdx.x;
  if (t < SCAN_NB) tmp[t] = bsum[t];
  __syncthreads();
  if (t == 0) {
    int run = 0;
    for (int i = 0; i < SCAN_NB; ++i) { int x = tmp[i]; tmp[i] = run; run += x; }
  }
  __syncthreads();
  if (t < SCAN_NB) boff[t] = tmp[t];
}

__global__ __launch_bounds__(256)
void scan_apply_kernel(const int* __restrict__ deg, const int* __restrict__ boff,
                       int* __restrict__ rowp, int* __restrict__ cur) {
  __shared__ int ws[4];
  const int t = threadIdx.x;
  const int lane = t & 63, w = t >> 6;
  const int i = blockIdx.x * 256 + t;
  int v = (i < N_NODES) ? deg[i] : 0;
  int inc = v;
#pragma unroll
  for (int off = 1; off < 64; off <<= 1) {
    int u = __shfl_up(inc, off);
    if (lane >= off) inc += u;
  }
  if (lane == 63) ws[w] = inc;
  __syncthreads();
  int add = boff[blockIdx.x];
#pragma unroll
  for (int k = 0; k < 4; ++k)
    if (k < w) add += ws[k];
  int exc = add + inc - v;
  if (i < N_NODES) {
    rowp[i] = exc;
    cur[i] = exc;
    if (i == N_NODES - 1) rowp[N_NODES] = exc + v;
  }
}

__global__ void scatter_kernel(const int* __restrict__ ei, int* __restrict__ cur,
                               int* __restrict__ colb) {
  int e = blockIdx.x * blockDim.x + threadIdx.x;
  if (e >= TOT_E) return;
  int src, dst;
  if (e < E_EDGES) { src = ei[e]; dst = ei[E_EDGES + e]; }
  else             { src = dst = e - E_EDGES; }
  int pos = atomicAdd(&cur[dst], 1);
  colb[pos] = src;
}

// ---------- conversions + deg zeroing (one grid) ----------
__global__ __launch_bounds__(256)
void conv_inputs_kernel(const float* __restrict__ W1, const float* __restrict__ W2,
                        const float* __restrict__ x, ushort* __restrict__ Wt1,
                        ushort* __restrict__ Wt2, ushort* __restrict__ xb,
                        int* __restrict__ deg) {
  const int b = blockIdx.x;
  if (b < 512) {
    const float* W = (b < 256) ? W1 : W2;
    ushort* Wt = (b < 256) ? Wt1 : Wt2;
    const int n = b & 255;
    const int k = threadIdx.x;
    Wt[n * 256 + k] = f2bf(W[k * 256 + n]);
  } else if (b < 512 + N_NODES * 256 / 8 / 256) {
    int idx = (b - 512) * 256 + threadIdx.x;  // granule of 8
    size_t base = (size_t)idx * 8;
    float4 a = *reinterpret_cast<const float4*>(x + base);
    float4 c = *reinterpret_cast<const float4*>(x + base + 4);
    short8 o;
    o[0] = f2bf(a.x); o[1] = f2bf(a.y); o[2] = f2bf(a.z); o[3] = f2bf(a.w);
    o[4] = f2bf(c.x); o[5] = f2bf(c.y); o[6] = f2bf(c.z); o[7] = f2bf(c.w);
    *reinterpret_cast<short8*>(xb + base) = o;
  } else {
    int idx = (b - (512 + N_NODES * 256 / 8 / 256)) * 256 + threadIdx.x;
    if (idx < N_NODES) deg[idx] = 0;
  }
}

// ---------- bf16-MFMA GEMM (pipelined, barrier-free) + alpha epilogue ----------
__global__ __launch_bounds__(256)
void gemm_alpha_kernel(const ushort* __restrict__ Ab, const ushort* __restrict__ Wt,
                       const float* __restrict__ asrc, const float* __restrict__ adst,
                       ushort* __restrict__ hout, float* __restrict__ as_,
                       float* __restrict__ ad_) {
  __shared__ ushort hs[32 * 256];  // 16 KB repack buffer

  const int t = threadIdx.x;
  const int w = t >> 6;
  const int l = t & 63;
  const int row0 = blockIdx.x * 32;

  const ushort* abase = Ab + (size_t)(row0 + (l & 15)) * 256 + ((l >> 4) * 8);
  const ushort* bbase = Wt + (size_t)(w * 64 + (l & 15)) * 256 + ((l >> 4) * 8);

  f32x4 acc[2][4];
#pragma unroll
  for (int i = 0; i < 2; ++i)
#pragma unroll
    for (int j = 0; j < 4; ++j) acc[i][j] = (f32x4){0.f, 0.f, 0.f, 0.f};

  short8 a0 = *reinterpret_cast<const short8*>(abase);
  short8 a1 = *reinterpret_cast<const short8*>(abase + 16 * 256);
  short8 b0 = *reinterpret_cast<const short8*>(bbase);
  short8 b1 = *reinterpret_cast<const short8*>(bbase + 16 * 256);
  short8 b2 = *reinterpret_cast<const short8*>(bbase + 32 * 256);
  short8 b3 = *reinterpret_cast<const short8*>(bbase + 48 * 256);
#pragma unroll
  for (int kk = 0; kk < 256; kk += 32) {
    short8 na0, na1, nb0, nb1, nb2, nb3;
    if (kk + 32 < 256) {
      na0 = *reinterpret_cast<const short8*>(abase + kk + 32);
      na1 = *reinterpret_cast<const short8*>(abase + 16 * 256 + kk + 32);
      nb0 = *reinterpret_cast<const short8*>(bbase + kk + 32);
      nb1 = *reinterpret_cast<const short8*>(bbase + 16 * 256 + kk + 32);
      nb2 = *reinterpret_cast<const short8*>(bbase + 32 * 256 + kk + 32);
      nb3 = *reinterpret_cast<const short8*>(bbase + 48 * 256 + kk + 32);
    }
    acc[0][0] = __builtin_amdgcn_mfma_f32_16x16x32_bf16(a0, b0, acc[0][0], 0, 0, 0);
    acc[0][1] = __builtin_amdgcn_mfma_f32_16x16x32_bf16(a0, b1, acc[0][1], 0, 0, 0);
    acc[0][2] = __builtin_amdgcn_mfma_f32_16x16x32_bf16(a0, b2, acc[0][2], 0, 0, 0);
    acc[0][3] = __builtin_amdgcn_mfma_f32_16x16x32_bf16(a0, b3, acc[0][3], 0, 0, 0);
    acc[1][0] = __builtin_amdgcn_mfma_f32_16x16x32_bf16(a1, b0, acc[1][0], 0, 0, 0);
    acc[1][1] = __builtin_amdgcn_mfma_f32_16x16x32_bf16(a1, b1, acc[1][1], 0, 0, 0);
    acc[1][2] = __builtin_amdgcn_mfma_f32_16x16x32_bf16(a1, b2, acc[1][2], 0, 0, 0);
    acc[1][3] = __builtin_amdgcn_mfma_f32_16x16x32_bf16(a1, b3, acc[1][3], 0, 0, 0);
    if (kk + 32 < 256) {
      a0 = na0; a1 = na1; b0 = nb0; b1 = nb1; b2 = nb2; b3 = nb3;
    }
  }

  // ---- alpha epilogue ----
  float asj[4], adj[4];
#pragma unroll
  for (int j = 0; j < 4; ++j) {
    asj[j] = asrc[w * 64 + j * 16 + (l & 15)];
    adj[j] = adst[w * 64 + j * 16 + (l & 15)];
  }
#pragma unroll
  for (int i = 0; i < 2; ++i) {
#pragma unroll
    for (int q = 0; q < 4; ++q) {
      float ps = 0.f, pd = 0.f;
#pragma unroll
      for (int j = 0; j < 4; ++j) {
        ps += acc[i][j][q] * asj[j];
        pd += acc[i][j][q] * adj[j];
      }
#pragma unroll
      for (int off = 1; off < 16; off <<= 1) {
        ps += __shfl_xor(ps, off);
        pd += __shfl_xor(pd, off);
      }
      int row = row0 + i * 16 + (l >> 4) * 4 + q;
      if ((l & 15) == 0) {
        as_[row * 4 + w] = ps;
        ad_[row * 4 + w] = pd;
      }
    }
  }

  // ---- h repack: fragments -> LDS bf16 -> coalesced global ----
#pragma unroll
  for (int i = 0; i < 2; ++i)
#pragma unroll
    for (int j = 0; j < 4; ++j)
#pragma unroll
      for (int q = 0; q < 4; ++q) {
        int row = i * 16 + (l >> 4) * 4 + q;
        int col = w * 64 + j * 16 + (l & 15);
        hs[row * 256 + col] = f2bf(acc[i][j][q]);
      }
  __syncthreads();
#pragma unroll
  for (int g = 0; g < 4; ++g) {
    int gi = g * 256 + t;
    int row = gi >> 5;
    int slot = gi & 31;
    *reinterpret_cast<short8*>(hout + (size_t)(row0 + row) * 256 + slot * 8) =
        *reinterpret_cast<const short8*>(&hs[row * 256 + slot * 8]);
  }
}

// ---------- FUSED attn softmax + gather + bias + LN (+resid) + ELU (+score) ----
// Wave per dst (4/block). Pass A: strided per-head max. Pass B: serial gather
// with inline w=exp(e-M); z accumulated locally (every lane sees all edges).
__global__ __launch_bounds__(256)
void attn_gather_ln_kernel(const ushort* __restrict__ h, const float* __restrict__ as_,
                           const float* __restrict__ ad_, const int* __restrict__ rowp,
                           const int* __restrict__ colb, const float* __restrict__ bias,
                           const float* __restrict__ gamma, const float* __restrict__ beta,
                           const ushort* __restrict__ residb, ushort* __restrict__ outb,
                           const float* __restrict__ aw, const float* __restrict__ ab,
                           float* __restrict__ score) {
  const int t = threadIdx.x;
  const int d = blockIdx.x * 4 + (t >> 6);
  const int l = t & 63;
  const int start = rowp[d];
  const int deg = rowp[d + 1] - start;

  // ---- pass A: per-head max, mapping (edge residue l>>2, head l&3) ----
  const int e16 = l >> 2, hh = l & 3;
  const float adv = ad_[d * 4 + hh];
  float M = -INFINITY;
  for (int i = e16; i < deg; i += 16) {
    int s = colb[start + i];
    float e = as_[s * 4 + hh] + adv;
    e = (e >= 0.f) ? e : 0.2f * e;
    M = fmaxf(M, e);
  }
#pragma unroll
  for (int off = 4; off < 64; off <<= 1) M = fmaxf(M, __shfl_xor(M, off));

  // ---- hand each gather lane its head's M / ad (lane k<4 holds head k) ----
  const int gh = l >> 4;            // gather head for channels l*4..l*4+3
  const float Mg = __shfl(M, gh);
  const float adg = __shfl(adv, gh);

  // ---- pass B: serial weighted gather, local z ----
  float a0 = 0.f, a1 = 0.f, a2 = 0.f, a3 = 0.f, z = 0.f;
  const int c0 = l * 4;
  const ushort* hrow = h + c0;
#pragma unroll 2
  for (int i = 0; i < deg; ++i) {
    int s = colb[start + i];
    float e = as_[s * 4 + gh] + adg;
    e = (e >= 0.f) ? e : 0.2f * e;
    float wv = __expf(e - Mg);
    z += wv;
    uint2 hv = *reinterpret_cast<const uint2*>(hrow + (size_t)s * 256);
    a0 += wv * bflo(hv.x);
    a1 += wv * bfhi(hv.x);
    a2 += wv * bflo(hv.y);
    a3 += wv * bfhi(hv.y);
  }
  const float zi = 1.f / (z + 1e-16f);
  float4 bi = *reinterpret_cast<const float4*>(bias + c0);
  float v0 = a0 * zi + bi.x, v1 = a1 * zi + bi.y;
  float v2 = a2 * zi + bi.z, v3 = a3 * zi + bi.w;

  float s1 = wave_sum(v0 + v1 + v2 + v3);
  float s2 = wave_sum(v0 * v0 + v1 * v1 + v2 * v2 + v3 * v3);
  float mu = s1 * (1.f / 256.f);
  float var = s2 * (1.f / 256.f) - mu * mu;
  float rstd = rsqrtf(var + 1e-5f);
  float4 ga = *reinterpret_cast<const float4*>(gamma + c0);
  float4 be = *reinterpret_cast<const float4*>(beta + c0);
  float y0 = (v0 - mu) * rstd * ga.x + be.x;
  float y1 = (v1 - mu) * rstd * ga.y + be.y;
  float y2 = (v2 - mu) * rstd * ga.z + be.z;
  float y3 = (v3 - mu) * rstd * ga.w + be.w;
  if (residb) {
    uint2 rv = *reinterpret_cast<const uint2*>(residb + (size_t)d * 256 + c0);
    y0 += bflo(rv.x); y1 += bfhi(rv.x); y2 += bflo(rv.y); y3 += bfhi(rv.y);
  }
  y0 = (y0 > 0.f) ? y0 : expm1f(y0);
  y1 = (y1 > 0.f) ? y1 : expm1f(y1);
  y2 = (y2 > 0.f) ? y2 : expm1f(y2);
  y3 = (y3 > 0.f) ? y3 : expm1f(y3);

  uint2 o;
  o.x = ((unsigned)f2bf(y0)) | (((unsigned)f2bf(y1)) << 16);
  o.y = ((unsigned)f2bf(y2)) | (((unsigned)f2bf(y3)) << 16);
  *reinterpret_cast<uint2*>(outb + (size_t)d * 256 + c0) = o;

  if (score) {
    float4 aww = *reinterpret_cast<const float4*>(aw + c0);
    float sp = wave_sum(y0 * aww.x + y1 * aww.y + y2 * aww.z + y3 * aww.w);
    if (l == 0) score[d] = sp + ab[0];
  }
}

// ---------- pooling softmax: parallel partials + combine ----------
__global__ __launch_bounds__(256)
void score_part_kernel(const float* __restrict__ s, float* __restrict__ pm,
                       float* __restrict__ pz) {
  __shared__ float red[4];
  const int t = threadIdx.x, b = blockIdx.x;
  const int lane = t & 63, wid = t >> 6;
  float m = -INFINITY;
  for (int n = b * 256 + t; n < N_NODES; n += SPART * 256) m = fmaxf(m, s[n]);
#pragma unroll
  for (int off = 32; off; off >>= 1) m = fmaxf(m, __shfl_xor(m, off));
  if (lane == 0) red[wid] = m;
  __syncthreads();
  m = fmaxf(fmaxf(red[0], red[1]), fmaxf(red[2], red[3]));
  __syncthreads();
  float z = 0.f;
  for (int n = b * 256 + t; n < N_NODES; n += SPART * 256) z += __expf(s[n] - m);
  z = wave_sum(z);
  if (lane == 0) red[wid] = z;
  __syncthreads();
  if (t == 0) { pm[b] = m; pz[b] = red[0] + red[1] + red[2] + red[3]; }
}

__global__ __launch_bounds__(64)
void score_comb_kernel(const float* __restrict__ pm, const float* __restrict__ pz,
                       float* __restrict__ mz) {
  const int l = threadIdx.x;
  float m = (l < SPART) ? pm[l] : -INFINITY;
#pragma unroll
  for (int off = 32; off; off >>= 1) m = fmaxf(m, __shfl_xor(m, off));
  float z = (l < SPART) ? pz[l] * __expf(pm[l] - m) : 0.f;
  z = wave_sum(z);
  if (l == 0) { mz[0] = m; mz[1] = z; }
}

__global__ __launch_bounds__(256)
void pool_partial_kernel(const ushort* __restrict__ hb2, const float* __restrict__ s,
                         const float* __restrict__ mz, float* __restrict__ part) {
  __shared__ float red4[4][256];
  const int t = threadIdx.x, b = blockIdx.x;
  const int c4 = t & 63, rsub = t >> 6;
  const float m = mz[0];
  const float invz = 1.f / mz[1];
  f32x4 acc = (f32x4){0.f, 0.f, 0.f, 0.f};
  for (int n = b * 4 + rsub; n < N_NODES; n += 1024) {
    float w = __expf(s[n] - m);
    uint2 hv = *reinterpret_cast<const uint2*>(hb2 + (size_t)n * 256 + c4 * 4);
    acc[0] += w * bflo(hv.x);
    acc[1] += w * bfhi(hv.x);
    acc[2] += w * bflo(hv.y);
    acc[3] += w * bfhi(hv.y);
  }
#pragma unroll
  for (int k = 0; k < 4; ++k) red4[rsub][c4 * 4 + k] = acc[k];
  __syncthreads();
  if (t < 256) {
    float v = red4[0][t] + red4[1][t] + red4[2][t] + red4[3][t];
    part[b * 256 + t] = v * invz;
  }
}

__global__ __launch_bounds__(256)
void pool_final_kernel(const float* __restrict__ part, float* __restrict__ out) {
  const int t = threadIdx.x;
  float acc = 0.f;
  for (int b = 0; b < 256; ++b) acc += part[b * 256 + t];
  out[t] = acc;
}

extern "C" void kernel_launch(void* const* d_in, const int* in_sizes, int n_in,
                              void* d_out, int out_size, void* d_ws, size_t ws_size,
                              hipStream_t stream) {
  const float* x      = (const float*)d_in[0];
  const int*   ei     = (const int*)d_in[1];
  const float* W1     = (const float*)d_in[2];
  const float* b1     = (const float*)d_in[3];
  const float* a_src1 = (const float*)d_in[4];
  const float* a_dst1 = (const float*)d_in[5];
  const float* W2     = (const float*)d_in[6];
  const float* b2     = (const float*)d_in[7];
  const float* a_src2 = (const float*)d_in[8];
  const float* a_dst2 = (const float*)d_in[9];
  const float* g1     = (const float*)d_in[10];
  const float* be1    = (const float*)d_in[11];
  const float* g2     = (const float*)d_in[12];
  const float* be2    = (const float*)d_in[13];
  const float* attn_w = (const float*)d_in[14];
  const float* attn_b = (const float*)d_in[15];
  float* out = (float*)d_out;

  char* p = (char*)d_ws;
  auto alloc = [&](size_t bytes) {
    char* r = p;
    p += (bytes + 255) & ~size_t(255);
    return r;
  };
  ushort* h   = (ushort*)alloc((size_t)N_NODES * 256 * 2);
  ushort* xb  = (ushort*)alloc((size_t)N_NODES * 256 * 2);
  ushort* xb1 = (ushort*)alloc((size_t)N_NODES * 256 * 2);
  ushort* hb2 = (ushort*)alloc((size_t)N_NODES * 256 * 2);
  float* as_  = (float*)alloc((size_t)N_NODES * 4 * 4);
  float* ad_  = (float*)alloc((size_t)N_NODES * 4 * 4);
  float* sbuf = (float*)alloc((size_t)N_NODES * 4);
  float* mz   = (float*)alloc(256);
  float* pm   = (float*)alloc((size_t)SPART * 4);
  float* pz   = (float*)alloc((size_t)SPART * 4);
  float* part = (float*)alloc((size_t)256 * 256 * 4);
  ushort* wt1 = (ushort*)alloc((size_t)256 * 256 * 2);
  ushort* wt2 = (ushort*)alloc((size_t)256 * 256 * 2);
  int* deg    = (int*)alloc((size_t)N_NODES * 4);
  int* rowp   = (int*)alloc((size_t)(N_NODES + 1) * 4);
  int* cur    = (int*)alloc((size_t)N_NODES * 4);
  int* colb   = (int*)alloc((size_t)TOT_E * 4);
  int* bsum   = (int*)alloc((size_t)SCAN_NB * 4);
  int* boff   = (int*)alloc((size_t)SCAN_NB * 4);

  const int EB = (TOT_E + 255) / 256;
  const int GB = N_NODES / 32;   // 625
  const int DB = N_NODES / 4;    // 5000
  const int XB = N_NODES * 256 / 8 / 256;  // 2500
  const int CONVB = 512 + XB + SCAN_NB;

  conv_inputs_kernel<<<CONVB, 256, 0, stream>>>(W1, W2, x, wt1, wt2, xb, deg);
  hist_kernel<<<EB, 256, 0, stream>>>(ei, deg);
  scan_blocks_kernel<<<SCAN_NB, 256, 0, stream>>>(deg, bsum);
  scan_tops_kernel<<<1, 128, 0, stream>>>(bsum, boff);
  scan_apply_kernel<<<SCAN_NB, 256, 0, stream>>>(deg, boff, rowp, cur);
  scatter_kernel<<<EB, 256, 0, stream>>>(ei, cur, colb);

  // layer 1
  gemm_alpha_kernel<<<GB, 256, 0, stream>>>(xb, wt1, a_src1, a_dst1, h, as_, ad_);
  attn_gather_ln_kernel<<<DB, 256, 0, stream>>>(h, as_, ad_, rowp, colb, b1, g1, be1,
                                                nullptr, xb1, nullptr, nullptr, nullptr);
  // layer 2
  gemm_alpha_kernel<<<GB, 256, 0, stream>>>(xb1, wt2, a_src2, a_dst2, h, as_, ad_);
  attn_gather_ln_kernel<<<DB, 256, 0, stream>>>(h, as_, ad_, rowp, colb, b2, g2, be2,
                                                xb1, hb2, attn_w, attn_b, sbuf);
  // pooling
  score_part_kernel<<<SPART, 256, 0, stream>>>(sbuf, pm, pz);
  score_comb_kernel<<<1, 64, 0, stream>>>(pm, pz, mz);
  pool_partial_kernel<<<256, 256, 0, stream>>>(hb2, sbuf, mz, part);
  pool_final_kernel<<<1, 256, 0, stream>>>(part, out);
}

// Round 8
// 184.328 us; speedup vs baseline: 2.5574x; 1.0524x over previous
//
#include <hip/hip_runtime.h>
#include <math.h>

#define N_NODES 20000
#define E_EDGES 320000
#define TOT_E   (E_EDGES + N_NODES)
#define DHID    256
#define NHEAD   4
#define SCAN_NB ((N_NODES + 255) / 256)   // 79
#define SPART   32

typedef float f32x4 __attribute__((ext_vector_type(4)));
typedef short short8 __attribute__((ext_vector_type(8)));
typedef unsigned short ushort;

// ---------- helpers ----------
__device__ __forceinline__ float wave_sum(float v) {
#pragma unroll
  for (int off = 32; off; off >>= 1) v += __shfl_xor(v, off);
  return v;
}
__device__ __forceinline__ ushort f2bf(float f) {  // RNE f32 -> bf16
  unsigned u = __float_as_uint(f);
  u += 0x7fffu + ((u >> 16) & 1u);
  return (ushort)(u >> 16);
}
__device__ __forceinline__ float bflo(unsigned u) {
  return __uint_as_float(u << 16);
}
__device__ __forceinline__ float bfhi(unsigned u) {
  return __uint_as_float(u & 0xffff0000u);
}

// ---------- CSR build ----------
__global__ void hist_kernel(const int* __restrict__ ei, int* __restrict__ deg) {
  int e = blockIdx.x * blockDim.x + threadIdx.x;
  if (e >= TOT_E) return;
  int dst = (e < E_EDGES) ? ei[E_EDGES + e] : (e - E_EDGES);
  atomicAdd(&deg[dst], 1);
}

__global__ __launch_bounds__(256)
void scan_blocks_kernel(const int* __restrict__ deg, int* __restrict__ bsum) {
  __shared__ int ws[4];
  const int t = threadIdx.x;
  const int i = blockIdx.x * 256 + t;
  int v = (i < N_NODES) ? deg[i] : 0;
  int s = v;
#pragma unroll
  for (int off = 32; off; off >>= 1) s += __shfl_xor(s, off);
  if ((t & 63) == 0) ws[t >> 6] = s;
  __syncthreads();
  if (t == 0) bsum[blockIdx.x] = ws[0] + ws[1] + ws[2] + ws[3];
}

__global__ __launch_bounds__(128)
void scan_tops_kernel(const int* __restrict__ bsum, int* __restrict__ boff) {
  __shared__ int tmp[SCAN_NB];
  const int t = threadIdx.x;
  if (t < SCAN_NB) tmp[t] = bsum[t];
  __syncthreads();
  if (t == 0) {
    int run = 0;
    for (int i = 0; i < SCAN_NB; ++i) { int x = tmp[i]; tmp[i] = run; run += x; }
  }
  __syncthreads();
  if (t < SCAN_NB) boff[t] = tmp[t];
}

__global__ __launch_bounds__(256)
void scan_apply_kernel(const int* __restrict__ deg, const int* __restrict__ boff,
                       int* __restrict__ rowp, int* __restrict__ cur) {
  __shared__ int ws[4];
  const int t = threadIdx.x;
  const int lane = t & 63, w = t >> 6;
  const int i = blockIdx.x * 256 + t;
  int v = (i < N_NODES) ? deg[i] : 0;
  int inc = v;
#pragma unroll
  for (int off = 1; off < 64; off <<= 1) {
    int u = __shfl_up(inc, off);
    if (lane >= off) inc += u;
  }
  if (lane == 63) ws[w] = inc;
  __syncthreads();
  int add = boff[blockIdx.x];
#pragma unroll
  for (int k = 0; k < 4; ++k)
    if (k < w) add += ws[k];
  int exc = add + inc - v;
  if (i < N_NODES) {
    rowp[i] = exc;
    cur[i] = exc;
    if (i == N_NODES - 1) rowp[N_NODES] = exc + v;
  }
}

__global__ void scatter_kernel(const int* __restrict__ ei, int* __restrict__ cur,
                               int* __restrict__ colb) {
  int e = blockIdx.x * blockDim.x + threadIdx.x;
  if (e >= TOT_E) return;
  int src, dst;
  if (e < E_EDGES) { src = ei[e]; dst = ei[E_EDGES + e]; }
  else             { src = dst = e - E_EDGES; }
  int pos = atomicAdd(&cur[dst], 1);
  colb[pos] = src;
}

// ---------- conversions + deg zeroing (one grid) ----------
__global__ __launch_bounds__(256)
void conv_inputs_kernel(const float* __restrict__ W1, const float* __restrict__ W2,
                        const float* __restrict__ x, ushort* __restrict__ Wt1,
                        ushort* __restrict__ Wt2, ushort* __restrict__ xb,
                        int* __restrict__ deg) {
  const int b = blockIdx.x;
  if (b < 512) {
    const float* W = (b < 256) ? W1 : W2;
    ushort* Wt = (b < 256) ? Wt1 : Wt2;
    const int n = b & 255;
    const int k = threadIdx.x;
    Wt[n * 256 + k] = f2bf(W[k * 256 + n]);
  } else if (b < 512 + N_NODES * 256 / 8 / 256) {
    int idx = (b - 512) * 256 + threadIdx.x;  // granule of 8
    size_t base = (size_t)idx * 8;
    float4 a = *reinterpret_cast<const float4*>(x + base);
    float4 c = *reinterpret_cast<const float4*>(x + base + 4);
    short8 o;
    o[0] = f2bf(a.x); o[1] = f2bf(a.y); o[2] = f2bf(a.z); o[3] = f2bf(a.w);
    o[4] = f2bf(c.x); o[5] = f2bf(c.y); o[6] = f2bf(c.z); o[7] = f2bf(c.w);
    *reinterpret_cast<short8*>(xb + base) = o;
  } else {
    int idx = (b - (512 + N_NODES * 256 / 8 / 256)) * 256 + threadIdx.x;
    if (idx < N_NODES) deg[idx] = 0;
  }
}

// ---------- bf16-MFMA GEMM (pipelined, barrier-free) + alpha epilogue ----------
__global__ __launch_bounds__(256)
void gemm_alpha_kernel(const ushort* __restrict__ Ab, const ushort* __restrict__ Wt,
                       const float* __restrict__ asrc, const float* __restrict__ adst,
                       ushort* __restrict__ hout, float* __restrict__ as_,
                       float* __restrict__ ad_) {
  __shared__ ushort hs[32 * 256];  // 16 KB repack buffer

  const int t = threadIdx.x;
  const int w = t >> 6;
  const int l = t & 63;
  const int row0 = blockIdx.x * 32;

  const ushort* abase = Ab + (size_t)(row0 + (l & 15)) * 256 + ((l >> 4) * 8);
  const ushort* bbase = Wt + (size_t)(w * 64 + (l & 15)) * 256 + ((l >> 4) * 8);

  f32x4 acc[2][4];
#pragma unroll
  for (int i = 0; i < 2; ++i)
#pragma unroll
    for (int j = 0; j < 4; ++j) acc[i][j] = (f32x4){0.f, 0.f, 0.f, 0.f};

  short8 a0 = *reinterpret_cast<const short8*>(abase);
  short8 a1 = *reinterpret_cast<const short8*>(abase + 16 * 256);
  short8 b0 = *reinterpret_cast<const short8*>(bbase);
  short8 b1 = *reinterpret_cast<const short8*>(bbase + 16 * 256);
  short8 b2 = *reinterpret_cast<const short8*>(bbase + 32 * 256);
  short8 b3 = *reinterpret_cast<const short8*>(bbase + 48 * 256);
#pragma unroll
  for (int kk = 0; kk < 256; kk += 32) {
    short8 na0, na1, nb0, nb1, nb2, nb3;
    if (kk + 32 < 256) {
      na0 = *reinterpret_cast<const short8*>(abase + kk + 32);
      na1 = *reinterpret_cast<const short8*>(abase + 16 * 256 + kk + 32);
      nb0 = *reinterpret_cast<const short8*>(bbase + kk + 32);
      nb1 = *reinterpret_cast<const short8*>(bbase + 16 * 256 + kk + 32);
      nb2 = *reinterpret_cast<const short8*>(bbase + 32 * 256 + kk + 32);
      nb3 = *reinterpret_cast<const short8*>(bbase + 48 * 256 + kk + 32);
    }
    acc[0][0] = __builtin_amdgcn_mfma_f32_16x16x32_bf16(a0, b0, acc[0][0], 0, 0, 0);
    acc[0][1] = __builtin_amdgcn_mfma_f32_16x16x32_bf16(a0, b1, acc[0][1], 0, 0, 0);
    acc[0][2] = __builtin_amdgcn_mfma_f32_16x16x32_bf16(a0, b2, acc[0][2], 0, 0, 0);
    acc[0][3] = __builtin_amdgcn_mfma_f32_16x16x32_bf16(a0, b3, acc[0][3], 0, 0, 0);
    acc[1][0] = __builtin_amdgcn_mfma_f32_16x16x32_bf16(a1, b0, acc[1][0], 0, 0, 0);
    acc[1][1] = __builtin_amdgcn_mfma_f32_16x16x32_bf16(a1, b1, acc[1][1], 0, 0, 0);
    acc[1][2] = __builtin_amdgcn_mfma_f32_16x16x32_bf16(a1, b2, acc[1][2], 0, 0, 0);
    acc[1][3] = __builtin_amdgcn_mfma_f32_16x16x32_bf16(a1, b3, acc[1][3], 0, 0, 0);
    if (kk + 32 < 256) {
      a0 = na0; a1 = na1; b0 = nb0; b1 = nb1; b2 = nb2; b3 = nb3;
    }
  }

  // ---- alpha epilogue ----
  float asj[4], adj[4];
#pragma unroll
  for (int j = 0; j < 4; ++j) {
    asj[j] = asrc[w * 64 + j * 16 + (l & 15)];
    adj[j] = adst[w * 64 + j * 16 + (l & 15)];
  }
#pragma unroll
  for (int i = 0; i < 2; ++i) {
#pragma unroll
    for (int q = 0; q < 4; ++q) {
      float ps = 0.f, pd = 0.f;
#pragma unroll
      for (int j = 0; j < 4; ++j) {
        ps += acc[i][j][q] * asj[j];
        pd += acc[i][j][q] * adj[j];
      }
#pragma unroll
      for (int off = 1; off < 16; off <<= 1) {
        ps += __shfl_xor(ps, off);
        pd += __shfl_xor(pd, off);
      }
      int row = row0 + i * 16 + (l >> 4) * 4 + q;
      if ((l & 15) == 0) {
        as_[row * 4 + w] = ps;
        ad_[row * 4 + w] = pd;
      }
    }
  }

  // ---- h repack: fragments -> LDS bf16 -> coalesced global ----
#pragma unroll
  for (int i = 0; i < 2; ++i)
#pragma unroll
    for (int j = 0; j < 4; ++j)
#pragma unroll
      for (int q = 0; q < 4; ++q) {
        int row = i * 16 + (l >> 4) * 4 + q;
        int col = w * 64 + j * 16 + (l & 15);
        hs[row * 256 + col] = f2bf(acc[i][j][q]);
      }
  __syncthreads();
#pragma unroll
  for (int g = 0; g < 4; ++g) {
    int gi = g * 256 + t;
    int row = gi >> 5;
    int slot = gi & 31;
    *reinterpret_cast<short8*>(hout + (size_t)(row0 + row) * 256 + slot * 8) =
        *reinterpret_cast<const short8*>(&hs[row * 256 + slot * 8]);
  }
}

// ---------- FUSED attn softmax + gather + bias + LN (+resid) + ELU (+score) ----
// Wave per dst (4/block). Pass A: strided per-head max. Pass B: 4-way manually
// pipelined gather (4 independent colb->as_/h chains in flight) for MLP.
__global__ __launch_bounds__(256)
void attn_gather_ln_kernel(const ushort* __restrict__ h, const float* __restrict__ as_,
                           const float* __restrict__ ad_, const int* __restrict__ rowp,
                           const int* __restrict__ colb, const float* __restrict__ bias,
                           const float* __restrict__ gamma, const float* __restrict__ beta,
                           const ushort* __restrict__ residb, ushort* __restrict__ outb,
                           const float* __restrict__ aw, const float* __restrict__ ab,
                           float* __restrict__ score) {
  const int t = threadIdx.x;
  const int d = blockIdx.x * 4 + (t >> 6);
  const int l = t & 63;
  const int start = rowp[d];
  const int deg = rowp[d + 1] - start;

  // ---- pass A: per-head max, mapping (edge residue l>>2, head l&3) ----
  const int e16 = l >> 2, hh = l & 3;
  const float adv = ad_[d * 4 + hh];
  float M = -INFINITY;
  for (int i = e16; i < deg; i += 16) {
    int s = colb[start + i];
    float e = as_[s * 4 + hh] + adv;
    e = (e >= 0.f) ? e : 0.2f * e;
    M = fmaxf(M, e);
  }
#pragma unroll
  for (int off = 4; off < 64; off <<= 1) M = fmaxf(M, __shfl_xor(M, off));

  // ---- hand each gather lane its head's M / ad (lane k<4 holds head k) ----
  const int gh = l >> 4;            // gather head for channels l*4..l*4+3
  const float Mg = __shfl(M, gh);
  const float adg = __shfl(adv, gh);

  // ---- pass B: 4-way pipelined weighted gather, local z ----
  float a0 = 0.f, a1 = 0.f, a2 = 0.f, a3 = 0.f, z = 0.f;
  const int c0 = l * 4;
  const ushort* hrow = h + c0;
  const int* cb = colb + start;

  int i = 0;
  for (; i + 4 <= deg; i += 4) {
    // 4 independent address chains in flight
    int s0 = cb[i], s1 = cb[i + 1], s2 = cb[i + 2], s3 = cb[i + 3];
    float e0 = as_[s0 * 4 + gh];
    float e1 = as_[s1 * 4 + gh];
    float e2 = as_[s2 * 4 + gh];
    float e3 = as_[s3 * 4 + gh];
    uint2 h0 = *reinterpret_cast<const uint2*>(hrow + (size_t)s0 * 256);
    uint2 h1 = *reinterpret_cast<const uint2*>(hrow + (size_t)s1 * 256);
    uint2 h2 = *reinterpret_cast<const uint2*>(hrow + (size_t)s2 * 256);
    uint2 h3 = *reinterpret_cast<const uint2*>(hrow + (size_t)s3 * 256);
    e0 += adg; e0 = (e0 >= 0.f) ? e0 : 0.2f * e0;
    e1 += adg; e1 = (e1 >= 0.f) ? e1 : 0.2f * e1;
    e2 += adg; e2 = (e2 >= 0.f) ? e2 : 0.2f * e2;
    e3 += adg; e3 = (e3 >= 0.f) ? e3 : 0.2f * e3;
    float w0 = __expf(e0 - Mg), w1 = __expf(e1 - Mg);
    float w2 = __expf(e2 - Mg), w3 = __expf(e3 - Mg);
    z += w0 + w1 + w2 + w3;
    a0 += w0 * bflo(h0.x) + w1 * bflo(h1.x) + w2 * bflo(h2.x) + w3 * bflo(h3.x);
    a1 += w0 * bfhi(h0.x) + w1 * bfhi(h1.x) + w2 * bfhi(h2.x) + w3 * bfhi(h3.x);
    a2 += w0 * bflo(h0.y) + w1 * bflo(h1.y) + w2 * bflo(h2.y) + w3 * bflo(h3.y);
    a3 += w0 * bfhi(h0.y) + w1 * bfhi(h1.y) + w2 * bfhi(h2.y) + w3 * bfhi(h3.y);
  }
  for (; i < deg; ++i) {
    int s = cb[i];
    float e = as_[s * 4 + gh] + adg;
    e = (e >= 0.f) ? e : 0.2f * e;
    float wv = __expf(e - Mg);
    z += wv;
    uint2 hv = *reinterpret_cast<const uint2*>(hrow + (size_t)s * 256);
    a0 += wv * bflo(hv.x);
    a1 += wv * bfhi(hv.x);
    a2 += wv * bflo(hv.y);
    a3 += wv * bfhi(hv.y);
  }

  const float zi = 1.f / (z + 1e-16f);
  float4 bi = *reinterpret_cast<const float4*>(bias + c0);
  float v0 = a0 * zi + bi.x, v1 = a1 * zi + bi.y;
  float v2 = a2 * zi + bi.z, v3 = a3 * zi + bi.w;

  float s1 = wave_sum(v0 + v1 + v2 + v3);
  float s2 = wave_sum(v0 * v0 + v1 * v1 + v2 * v2 + v3 * v3);
  float mu = s1 * (1.f / 256.f);
  float var = s2 * (1.f / 256.f) - mu * mu;
  float rstd = rsqrtf(var + 1e-5f);
  float4 ga = *reinterpret_cast<const float4*>(gamma + c0);
  float4 be = *reinterpret_cast<const float4*>(beta + c0);
  float y0 = (v0 - mu) * rstd * ga.x + be.x;
  float y1 = (v1 - mu) * rstd * ga.y + be.y;
  float y2 = (v2 - mu) * rstd * ga.z + be.z;
  float y3 = (v3 - mu) * rstd * ga.w + be.w;
  if (residb) {
    uint2 rv = *reinterpret_cast<const uint2*>(residb + (size_t)d * 256 + c0);
    y0 += bflo(rv.x); y1 += bfhi(rv.x); y2 += bflo(rv.y); y3 += bfhi(rv.y);
  }
  y0 = (y0 > 0.f) ? y0 : expm1f(y0);
  y1 = (y1 > 0.f) ? y1 : expm1f(y1);
  y2 = (y2 > 0.f) ? y2 : expm1f(y2);
  y3 = (y3 > 0.f) ? y3 : expm1f(y3);

  uint2 o;
  o.x = ((unsigned)f2bf(y0)) | (((unsigned)f2bf(y1)) << 16);
  o.y = ((unsigned)f2bf(y2)) | (((unsigned)f2bf(y3)) << 16);
  *reinterpret_cast<uint2*>(outb + (size_t)d * 256 + c0) = o;

  if (score) {
    float4 aww = *reinterpret_cast<const float4*>(aw + c0);
    float sp = wave_sum(y0 * aww.x + y1 * aww.y + y2 * aww.z + y3 * aww.w);
    if (l == 0) score[d] = sp + ab[0];
  }
}

// ---------- pooling softmax: parallel partials + combine ----------
__global__ __launch_bounds__(256)
void score_part_kernel(const float* __restrict__ s, float* __restrict__ pm,
                       float* __restrict__ pz) {
  __shared__ float red[4];
  const int t = threadIdx.x, b = blockIdx.x;
  const int lane = t & 63, wid = t >> 6;
  float m = -INFINITY;
  for (int n = b * 256 + t; n < N_NODES; n += SPART * 256) m = fmaxf(m, s[n]);
#pragma unroll
  for (int off = 32; off; off >>= 1) m = fmaxf(m, __shfl_xor(m, off));
  if (lane == 0) red[wid] = m;
  __syncthreads();
  m = fmaxf(fmaxf(red[0], red[1]), fmaxf(red[2], red[3]));
  __syncthreads();
  float z = 0.f;
  for (int n = b * 256 + t; n < N_NODES; n += SPART * 256) z += __expf(s[n] - m);
  z = wave_sum(z);
  if (lane == 0) red[wid] = z;
  __syncthreads();
  if (t == 0) { pm[b] = m; pz[b] = red[0] + red[1] + red[2] + red[3]; }
}

__global__ __launch_bounds__(64)
void score_comb_kernel(const float* __restrict__ pm, const float* __restrict__ pz,
                       float* __restrict__ mz) {
  const int l = threadIdx.x;
  float m = (l < SPART) ? pm[l] : -INFINITY;
#pragma unroll
  for (int off = 32; off; off >>= 1) m = fmaxf(m, __shfl_xor(m, off));
  float z = (l < SPART) ? pz[l] * __expf(pm[l] - m) : 0.f;
  z = wave_sum(z);
  if (l == 0) { mz[0] = m; mz[1] = z; }
}

__global__ __launch_bounds__(256)
void pool_partial_kernel(const ushort* __restrict__ hb2, const float* __restrict__ s,
                         const float* __restrict__ mz, float* __restrict__ part) {
  __shared__ float red4[4][256];
  const int t = threadIdx.x, b = blockIdx.x;
  const int c4 = t & 63, rsub = t >> 6;
  const float m = mz[0];
  const float invz = 1.f / mz[1];
  f32x4 acc = (f32x4){0.f, 0.f, 0.f, 0.f};
  for (int n = b * 4 + rsub; n < N_NODES; n += 1024) {
    float w = __expf(s[n] - m);
    uint2 hv = *reinterpret_cast<const uint2*>(hb2 + (size_t)n * 256 + c4 * 4);
    acc[0] += w * bflo(hv.x);
    acc[1] += w * bfhi(hv.x);
    acc[2] += w * bflo(hv.y);
    acc[3] += w * bfhi(hv.y);
  }
#pragma unroll
  for (int k = 0; k < 4; ++k) red4[rsub][c4 * 4 + k] = acc[k];
  __syncthreads();
  if (t < 256) {
    float v = red4[0][t] + red4[1][t] + red4[2][t] + red4[3][t];
    part[b * 256 + t] = v * invz;
  }
}

__global__ __launch_bounds__(256)
void pool_final_kernel(const float* __restrict__ part, float* __restrict__ out) {
  const int t = threadIdx.x;
  float acc = 0.f;
  for (int b = 0; b < 256; ++b) acc += part[b * 256 + t];
  out[t] = acc;
}

extern "C" void kernel_launch(void* const* d_in, const int* in_sizes, int n_in,
                              void* d_out, int out_size, void* d_ws, size_t ws_size,
                              hipStream_t stream) {
  const float* x      = (const float*)d_in[0];
  const int*   ei     = (const int*)d_in[1];
  const float* W1     = (const float*)d_in[2];
  const float* b1     = (const float*)d_in[3];
  const float* a_src1 = (const float*)d_in[4];
  const float* a_dst1 = (const float*)d_in[5];
  const float* W2     = (const float*)d_in[6];
  const float* b2     = (const float*)d_in[7];
  const float* a_src2 = (const float*)d_in[8];
  const float* a_dst2 = (const float*)d_in[9];
  const float* g1     = (const float*)d_in[10];
  const float* be1    = (const float*)d_in[11];
  const float* g2     = (const float*)d_in[12];
  const float* be2    = (const float*)d_in[13];
  const float* attn_w = (const float*)d_in[14];
  const float* attn_b = (const float*)d_in[15];
  float* out = (float*)d_out;

  char* p = (char*)d_ws;
  auto alloc = [&](size_t bytes) {
    char* r = p;
    p += (bytes + 255) & ~size_t(255);
    return r;
  };
  ushort* h   = (ushort*)alloc((size_t)N_NODES * 256 * 2);
  ushort* xb  = (ushort*)alloc((size_t)N_NODES * 256 * 2);
  ushort* xb1 = (ushort*)alloc((size_t)N_NODES * 256 * 2);
  ushort* hb2 = (ushort*)alloc((size_t)N_NODES * 256 * 2);
  float* as_  = (float*)alloc((size_t)N_NODES * 4 * 4);
  float* ad_  = (float*)alloc((size_t)N_NODES * 4 * 4);
  float* sbuf = (float*)alloc((size_t)N_NODES * 4);
  float* mz   = (float*)alloc(256);
  float* pm   = (float*)alloc((size_t)SPART * 4);
  float* pz   = (float*)alloc((size_t)SPART * 4);
  float* part = (float*)alloc((size_t)256 * 256 * 4);
  ushort* wt1 = (ushort*)alloc((size_t)256 * 256 * 2);
  ushort* wt2 = (ushort*)alloc((size_t)256 * 256 * 2);
  int* deg    = (int*)alloc((size_t)N_NODES * 4);
  int* rowp   = (int*)alloc((size_t)(N_NODES + 1) * 4);
  int* cur    = (int*)alloc((size_t)N_NODES * 4);
  int* colb   = (int*)alloc((size_t)TOT_E * 4);
  int* bsum   = (int*)alloc((size_t)SCAN_NB * 4);
  int* boff   = (int*)alloc((size_t)SCAN_NB * 4);

  const int EB = (TOT_E + 255) / 256;
  const int GB = N_NODES / 32;   // 625
  const int DB = N_NODES / 4;    // 5000
  const int XB = N_NODES * 256 / 8 / 256;  // 2500
  const int CONVB = 512 + XB + SCAN_NB;

  conv_inputs_kernel<<<CONVB, 256, 0, stream>>>(W1, W2, x, wt1, wt2, xb, deg);
  hist_kernel<<<EB, 256, 0, stream>>>(ei, deg);
  scan_blocks_kernel<<<SCAN_NB, 256, 0, stream>>>(deg, bsum);
  scan_tops_kernel<<<1, 128, 0, stream>>>(bsum, boff);
  scan_apply_kernel<<<SCAN_NB, 256, 0, stream>>>(deg, boff, rowp, cur);
  scatter_kernel<<<EB, 256, 0, stream>>>(ei, cur, colb);

  // layer 1
  gemm_alpha_kernel<<<GB, 256, 0, stream>>>(xb, wt1, a_src1, a_dst1, h, as_, ad_);
  attn_gather_ln_kernel<<<DB, 256, 0, stream>>>(h, as_, ad_, rowp, colb, b1, g1, be1,
                                                nullptr, xb1, nullptr, nullptr, nullptr);
  // layer 2
  gemm_alpha_kernel<<<GB, 256, 0, stream>>>(xb1, wt2, a_src2, a_dst2, h, as_, ad_);
  attn_gather_ln_kernel<<<DB, 256, 0, stream>>>(h, as_, ad_, rowp, colb, b2, g2, be2,
                                                xb1, hb2, attn_w, attn_b, sbuf);
  // pooling
  score_part_kernel<<<SPART, 256, 0, stream>>>(sbuf, pm, pz);
  score_comb_kernel<<<1, 64, 0, stream>>>(pm, pz, mz);
  pool_partial_kernel<<<256, 256, 0, stream>>>(hb2, sbuf, mz, part);
  pool_final_kernel<<<1, 256, 0, stream>>>(part, out);
}

// Round 9
// 173.591 us; speedup vs baseline: 2.7156x; 1.0619x over previous
//
#include <hip/hip_runtime.h>
#include <math.h>

#define N_NODES 20000
#define E_EDGES 320000
#define TOT_E   (E_EDGES + N_NODES)
#define DHID    256
#define NHEAD   4
#define SCAN_NB ((N_NODES + 255) / 256)   // 79
#define SPART   32
#define ECAP    128   // edges staged in LDS per chunk per dst

typedef float f32x4 __attribute__((ext_vector_type(4)));
typedef short short8 __attribute__((ext_vector_type(8)));
typedef unsigned short ushort;

// ---------- helpers ----------
__device__ __forceinline__ float wave_sum(float v) {
#pragma unroll
  for (int off = 32; off; off >>= 1) v += __shfl_xor(v, off);
  return v;
}
__device__ __forceinline__ ushort f2bf(float f) {  // RNE f32 -> bf16
  unsigned u = __float_as_uint(f);
  u += 0x7fffu + ((u >> 16) & 1u);
  return (ushort)(u >> 16);
}
__device__ __forceinline__ float bflo(unsigned u) {
  return __uint_as_float(u << 16);
}
__device__ __forceinline__ float bfhi(unsigned u) {
  return __uint_as_float(u & 0xffff0000u);
}

// ---------- CSR build ----------
__global__ void hist_kernel(const int* __restrict__ ei, int* __restrict__ deg) {
  int e = blockIdx.x * blockDim.x + threadIdx.x;
  if (e >= TOT_E) return;
  int dst = (e < E_EDGES) ? ei[E_EDGES + e] : (e - E_EDGES);
  atomicAdd(&deg[dst], 1);
}

__global__ __launch_bounds__(256)
void scan_blocks_kernel(const int* __restrict__ deg, int* __restrict__ bsum) {
  __shared__ int ws[4];
  const int t = threadIdx.x;
  const int i = blockIdx.x * 256 + t;
  int v = (i < N_NODES) ? deg[i] : 0;
  int s = v;
#pragma unroll
  for (int off = 32; off; off >>= 1) s += __shfl_xor(s, off);
  if ((t & 63) == 0) ws[t >> 6] = s;
  __syncthreads();
  if (t == 0) bsum[blockIdx.x] = ws[0] + ws[1] + ws[2] + ws[3];
}

__global__ __launch_bounds__(128)
void scan_tops_kernel(const int* __restrict__ bsum, int* __restrict__ boff) {
  __shared__ int tmp[SCAN_NB];
  const int t = threadIdx.x;
  if (t < SCAN_NB) tmp[t] = bsum[t];
  __syncthreads();
  if (t == 0) {
    int run = 0;
    for (int i = 0; i < SCAN_NB; ++i) { int x = tmp[i]; tmp[i] = run; run += x; }
  }
  __syncthreads();
  if (t < SCAN_NB) boff[t] = tmp[t];
}

__global__ __launch_bounds__(256)
void scan_apply_kernel(const int* __restrict__ deg, const int* __restrict__ boff,
                       int* __restrict__ rowp, int* __restrict__ cur) {
  __shared__ int ws[4];
  const int t = threadIdx.x;
  const int lane = t & 63, w = t >> 6;
  const int i = blockIdx.x * 256 + t;
  int v = (i < N_NODES) ? deg[i] : 0;
  int inc = v;
#pragma unroll
  for (int off = 1; off < 64; off <<= 1) {
    int u = __shfl_up(inc, off);
    if (lane >= off) inc += u;
  }
  if (lane == 63) ws[w] = inc;
  __syncthreads();
  int add = boff[blockIdx.x];
#pragma unroll
  for (int k = 0; k < 4; ++k)
    if (k < w) add += ws[k];
  int exc = add + inc - v;
  if (i < N_NODES) {
    rowp[i] = exc;
    cur[i] = exc;
    if (i == N_NODES - 1) rowp[N_NODES] = exc + v;
  }
}

__global__ void scatter_kernel(const int* __restrict__ ei, int* __restrict__ cur,
                               int* __restrict__ colb) {
  int e = blockIdx.x * blockDim.x + threadIdx.x;
  if (e >= TOT_E) return;
  int src, dst;
  if (e < E_EDGES) { src = ei[e]; dst = ei[E_EDGES + e]; }
  else             { src = dst = e - E_EDGES; }
  int pos = atomicAdd(&cur[dst], 1);
  colb[pos] = src;
}

// ---------- conversions + deg zeroing (one grid) ----------
__global__ __launch_bounds__(256)
void conv_inputs_kernel(const float* __restrict__ W1, const float* __restrict__ W2,
                        const float* __restrict__ x, ushort* __restrict__ Wt1,
                        ushort* __restrict__ Wt2, ushort* __restrict__ xb,
                        int* __restrict__ deg) {
  const int b = blockIdx.x;
  if (b < 512) {
    const float* W = (b < 256) ? W1 : W2;
    ushort* Wt = (b < 256) ? Wt1 : Wt2;
    const int n = b & 255;
    const int k = threadIdx.x;
    Wt[n * 256 + k] = f2bf(W[k * 256 + n]);
  } else if (b < 512 + N_NODES * 256 / 8 / 256) {
    int idx = (b - 512) * 256 + threadIdx.x;  // granule of 8
    size_t base = (size_t)idx * 8;
    float4 a = *reinterpret_cast<const float4*>(x + base);
    float4 c = *reinterpret_cast<const float4*>(x + base + 4);
    short8 o;
    o[0] = f2bf(a.x); o[1] = f2bf(a.y); o[2] = f2bf(a.z); o[3] = f2bf(a.w);
    o[4] = f2bf(c.x); o[5] = f2bf(c.y); o[6] = f2bf(c.z); o[7] = f2bf(c.w);
    *reinterpret_cast<short8*>(xb + base) = o;
  } else {
    int idx = (b - (512 + N_NODES * 256 / 8 / 256)) * 256 + threadIdx.x;
    if (idx < N_NODES) deg[idx] = 0;
  }
}

// ---------- bf16-MFMA GEMM (pipelined, barrier-free) + alpha epilogue ----------
__global__ __launch_bounds__(256)
void gemm_alpha_kernel(const ushort* __restrict__ Ab, const ushort* __restrict__ Wt,
                       const float* __restrict__ asrc, const float* __restrict__ adst,
                       ushort* __restrict__ hout, float* __restrict__ as_,
                       float* __restrict__ ad_) {
  __shared__ ushort hs[32 * 256];  // 16 KB repack buffer

  const int t = threadIdx.x;
  const int w = t >> 6;
  const int l = t & 63;
  const int row0 = blockIdx.x * 32;

  const ushort* abase = Ab + (size_t)(row0 + (l & 15)) * 256 + ((l >> 4) * 8);
  const ushort* bbase = Wt + (size_t)(w * 64 + (l & 15)) * 256 + ((l >> 4) * 8);

  f32x4 acc[2][4];
#pragma unroll
  for (int i = 0; i < 2; ++i)
#pragma unroll
    for (int j = 0; j < 4; ++j) acc[i][j] = (f32x4){0.f, 0.f, 0.f, 0.f};

  short8 a0 = *reinterpret_cast<const short8*>(abase);
  short8 a1 = *reinterpret_cast<const short8*>(abase + 16 * 256);
  short8 b0 = *reinterpret_cast<const short8*>(bbase);
  short8 b1 = *reinterpret_cast<const short8*>(bbase + 16 * 256);
  short8 b2 = *reinterpret_cast<const short8*>(bbase + 32 * 256);
  short8 b3 = *reinterpret_cast<const short8*>(bbase + 48 * 256);
#pragma unroll
  for (int kk = 0; kk < 256; kk += 32) {
    short8 na0, na1, nb0, nb1, nb2, nb3;
    if (kk + 32 < 256) {
      na0 = *reinterpret_cast<const short8*>(abase + kk + 32);
      na1 = *reinterpret_cast<const short8*>(abase + 16 * 256 + kk + 32);
      nb0 = *reinterpret_cast<const short8*>(bbase + kk + 32);
      nb1 = *reinterpret_cast<const short8*>(bbase + 16 * 256 + kk + 32);
      nb2 = *reinterpret_cast<const short8*>(bbase + 32 * 256 + kk + 32);
      nb3 = *reinterpret_cast<const short8*>(bbase + 48 * 256 + kk + 32);
    }
    acc[0][0] = __builtin_amdgcn_mfma_f32_16x16x32_bf16(a0, b0, acc[0][0], 0, 0, 0);
    acc[0][1] = __builtin_amdgcn_mfma_f32_16x16x32_bf16(a0, b1, acc[0][1], 0, 0, 0);
    acc[0][2] = __builtin_amdgcn_mfma_f32_16x16x32_bf16(a0, b2, acc[0][2], 0, 0, 0);
    acc[0][3] = __builtin_amdgcn_mfma_f32_16x16x32_bf16(a0, b3, acc[0][3], 0, 0, 0);
    acc[1][0] = __builtin_amdgcn_mfma_f32_16x16x32_bf16(a1, b0, acc[1][0], 0, 0, 0);
    acc[1][1] = __builtin_amdgcn_mfma_f32_16x16x32_bf16(a1, b1, acc[1][1], 0, 0, 0);
    acc[1][2] = __builtin_amdgcn_mfma_f32_16x16x32_bf16(a1, b2, acc[1][2], 0, 0, 0);
    acc[1][3] = __builtin_amdgcn_mfma_f32_16x16x32_bf16(a1, b3, acc[1][3], 0, 0, 0);
    if (kk + 32 < 256) {
      a0 = na0; a1 = na1; b0 = nb0; b1 = nb1; b2 = nb2; b3 = nb3;
    }
  }

  // ---- alpha epilogue ----
  float asj[4], adj[4];
#pragma unroll
  for (int j = 0; j < 4; ++j) {
    asj[j] = asrc[w * 64 + j * 16 + (l & 15)];
    adj[j] = adst[w * 64 + j * 16 + (l & 15)];
  }
#pragma unroll
  for (int i = 0; i < 2; ++i) {
#pragma unroll
    for (int q = 0; q < 4; ++q) {
      float ps = 0.f, pd = 0.f;
#pragma unroll
      for (int j = 0; j < 4; ++j) {
        ps += acc[i][j][q] * asj[j];
        pd += acc[i][j][q] * adj[j];
      }
#pragma unroll
      for (int off = 1; off < 16; off <<= 1) {
        ps += __shfl_xor(ps, off);
        pd += __shfl_xor(pd, off);
      }
      int row = row0 + i * 16 + (l >> 4) * 4 + q;
      if ((l & 15) == 0) {
        as_[row * 4 + w] = ps;
        ad_[row * 4 + w] = pd;
      }
    }
  }

  // ---- h repack: fragments -> LDS bf16 -> coalesced global ----
#pragma unroll
  for (int i = 0; i < 2; ++i)
#pragma unroll
    for (int j = 0; j < 4; ++j)
#pragma unroll
      for (int q = 0; q < 4; ++q) {
        int row = i * 16 + (l >> 4) * 4 + q;
        int col = w * 64 + j * 16 + (l & 15);
        hs[row * 256 + col] = f2bf(acc[i][j][q]);
      }
  __syncthreads();
#pragma unroll
  for (int g = 0; g < 4; ++g) {
    int gi = g * 256 + t;
    int row = gi >> 5;
    int slot = gi & 31;
    *reinterpret_cast<short8*>(hout + (size_t)(row0 + row) * 256 + slot * 8) =
        *reinterpret_cast<const short8*>(&hs[row * 256 + slot * 8]);
  }
}

// ---------- FUSED attn softmax + gather + bias + LN (+resid) + ELU (+score) ----
// Wave per dst (4/block). Shift-invariant softmax (no max pass; e clamped).
// Stage sweep (parallel, 16 edges x 4 heads): w=exp(e) + sidx -> wave-private
// LDS. Serial sweep: LDS-broadcast (sidx,w) + independent h-row loads.
__global__ __launch_bounds__(256)
void attn_gather_ln_kernel(const ushort* __restrict__ h, const float* __restrict__ as_,
                           const float* __restrict__ ad_, const int* __restrict__ rowp,
                           const int* __restrict__ colb, const float* __restrict__ bias,
                           const float* __restrict__ gamma, const float* __restrict__ beta,
                           const ushort* __restrict__ residb, ushort* __restrict__ outb,
                           const float* __restrict__ aw, const float* __restrict__ ab,
                           float* __restrict__ score) {
  __shared__ float ew[4][ECAP][NHEAD];  // 8 KB
  __shared__ int   sidx[4][ECAP];       // 2 KB

  const int t = threadIdx.x;
  const int wd = t >> 6;
  const int d = blockIdx.x * 4 + wd;
  const int l = t & 63;
  const int start = rowp[d];
  const int deg = rowp[d + 1] - start;
  const int* cb = colb + start;

  // staging mapping: (edge residue l>>2, head l&3)
  const int e16 = l >> 2, hh = l & 3;
  const float adv = ad_[d * 4 + hh];
  // gather mapping: lane l owns channels l*4..l*4+3, head gh = l>>4
  const int gh = l >> 4;
  const int c0 = l * 4;
  const ushort* hrow = h + c0;

  float zpart = 0.f;
  float a0 = 0.f, a1 = 0.f, a2 = 0.f, a3 = 0.f;

  for (int base = 0; base < deg; base += ECAP) {
    const int cnt = min(deg - base, ECAP);
    // ---- stage sweep: parallel over (16 edges, 4 heads) ----
    for (int i = e16; i < cnt; i += 16) {
      int s = cb[base + i];
      if (hh == 0) sidx[wd][i] = s;
      float e = as_[s * 4 + hh] + adv;
      e = (e >= 0.f) ? e : 0.2f * e;
      e = fminf(e, 60.f);                 // overflow insurance (shift-invariant)
      float wv = __expf(e);
      ew[wd][i][hh] = wv;
      zpart += wv;
    }
    // ---- serial sweep: LDS reads + independent h loads, 4-batched ----
    int i = 0;
    for (; i + 4 <= cnt; i += 4) {
      int s0 = sidx[wd][i], s1 = sidx[wd][i + 1];
      int s2 = sidx[wd][i + 2], s3 = sidx[wd][i + 3];
      float w0 = ew[wd][i][gh], w1 = ew[wd][i + 1][gh];
      float w2 = ew[wd][i + 2][gh], w3 = ew[wd][i + 3][gh];
      uint2 h0 = *reinterpret_cast<const uint2*>(hrow + (size_t)s0 * 256);
      uint2 h1 = *reinterpret_cast<const uint2*>(hrow + (size_t)s1 * 256);
      uint2 h2 = *reinterpret_cast<const uint2*>(hrow + (size_t)s2 * 256);
      uint2 h3 = *reinterpret_cast<const uint2*>(hrow + (size_t)s3 * 256);
      a0 += w0 * bflo(h0.x) + w1 * bflo(h1.x) + w2 * bflo(h2.x) + w3 * bflo(h3.x);
      a1 += w0 * bfhi(h0.x) + w1 * bfhi(h1.x) + w2 * bfhi(h2.x) + w3 * bfhi(h3.x);
      a2 += w0 * bflo(h0.y) + w1 * bflo(h1.y) + w2 * bflo(h2.y) + w3 * bflo(h3.y);
      a3 += w0 * bfhi(h0.y) + w1 * bfhi(h1.y) + w2 * bfhi(h2.y) + w3 * bfhi(h3.y);
    }
    for (; i < cnt; ++i) {
      int s = sidx[wd][i];
      float wv = ew[wd][i][gh];
      uint2 hv = *reinterpret_cast<const uint2*>(hrow + (size_t)s * 256);
      a0 += wv * bflo(hv.x);
      a1 += wv * bfhi(hv.x);
      a2 += wv * bflo(hv.y);
      a3 += wv * bfhi(hv.y);
    }
  }

  // z reduce across the 16 edge-residue groups (per head) then broadcast
#pragma unroll
  for (int off = 4; off < 64; off <<= 1) zpart += __shfl_xor(zpart, off);
  const float zi = 1.f / (__shfl(zpart, gh) + 1e-16f);

  float4 bi = *reinterpret_cast<const float4*>(bias + c0);
  float v0 = a0 * zi + bi.x, v1 = a1 * zi + bi.y;
  float v2 = a2 * zi + bi.z, v3 = a3 * zi + bi.w;

  float s1 = wave_sum(v0 + v1 + v2 + v3);
  float s2 = wave_sum(v0 * v0 + v1 * v1 + v2 * v2 + v3 * v3);
  float mu = s1 * (1.f / 256.f);
  float var = s2 * (1.f / 256.f) - mu * mu;
  float rstd = rsqrtf(var + 1e-5f);
  float4 ga = *reinterpret_cast<const float4*>(gamma + c0);
  float4 be = *reinterpret_cast<const float4*>(beta + c0);
  float y0 = (v0 - mu) * rstd * ga.x + be.x;
  float y1 = (v1 - mu) * rstd * ga.y + be.y;
  float y2 = (v2 - mu) * rstd * ga.z + be.z;
  float y3 = (v3 - mu) * rstd * ga.w + be.w;
  if (residb) {
    uint2 rv = *reinterpret_cast<const uint2*>(residb + (size_t)d * 256 + c0);
    y0 += bflo(rv.x); y1 += bfhi(rv.x); y2 += bflo(rv.y); y3 += bfhi(rv.y);
  }
  y0 = (y0 > 0.f) ? y0 : expm1f(y0);
  y1 = (y1 > 0.f) ? y1 : expm1f(y1);
  y2 = (y2 > 0.f) ? y2 : expm1f(y2);
  y3 = (y3 > 0.f) ? y3 : expm1f(y3);

  uint2 o;
  o.x = ((unsigned)f2bf(y0)) | (((unsigned)f2bf(y1)) << 16);
  o.y = ((unsigned)f2bf(y2)) | (((unsigned)f2bf(y3)) << 16);
  *reinterpret_cast<uint2*>(outb + (size_t)d * 256 + c0) = o;

  if (score) {
    float4 aww = *reinterpret_cast<const float4*>(aw + c0);
    float sp = wave_sum(y0 * aww.x + y1 * aww.y + y2 * aww.z + y3 * aww.w);
    if (l == 0) score[d] = sp + ab[0];
  }
}

// ---------- pooling softmax: parallel partials + combine ----------
__global__ __launch_bounds__(256)
void score_part_kernel(const float* __restrict__ s, float* __restrict__ pm,
                       float* __restrict__ pz) {
  __shared__ float red[4];
  const int t = threadIdx.x, b = blockIdx.x;
  const int lane = t & 63, wid = t >> 6;
  float m = -INFINITY;
  for (int n = b * 256 + t; n < N_NODES; n += SPART * 256) m = fmaxf(m, s[n]);
#pragma unroll
  for (int off = 32; off; off >>= 1) m = fmaxf(m, __shfl_xor(m, off));
  if (lane == 0) red[wid] = m;
  __syncthreads();
  m = fmaxf(fmaxf(red[0], red[1]), fmaxf(red[2], red[3]));
  __syncthreads();
  float z = 0.f;
  for (int n = b * 256 + t; n < N_NODES; n += SPART * 256) z += __expf(s[n] - m);
  z = wave_sum(z);
  if (lane == 0) red[wid] = z;
  __syncthreads();
  if (t == 0) { pm[b] = m; pz[b] = red[0] + red[1] + red[2] + red[3]; }
}

__global__ __launch_bounds__(64)
void score_comb_kernel(const float* __restrict__ pm, const float* __restrict__ pz,
                       float* __restrict__ mz) {
  const int l = threadIdx.x;
  float m = (l < SPART) ? pm[l] : -INFINITY;
#pragma unroll
  for (int off = 32; off; off >>= 1) m = fmaxf(m, __shfl_xor(m, off));
  float z = (l < SPART) ? pz[l] * __expf(pm[l] - m) : 0.f;
  z = wave_sum(z);
  if (l == 0) { mz[0] = m; mz[1] = z; }
}

__global__ __launch_bounds__(256)
void pool_partial_kernel(const ushort* __restrict__ hb2, const float* __restrict__ s,
                         const float* __restrict__ mz, float* __restrict__ part) {
  __shared__ float red4[4][256];
  const int t = threadIdx.x, b = blockIdx.x;
  const int c4 = t & 63, rsub = t >> 6;
  const float m = mz[0];
  const float invz = 1.f / mz[1];
  f32x4 acc = (f32x4){0.f, 0.f, 0.f, 0.f};
  for (int n = b * 4 + rsub; n < N_NODES; n += 1024) {
    float w = __expf(s[n] - m);
    uint2 hv = *reinterpret_cast<const uint2*>(hb2 + (size_t)n * 256 + c4 * 4);
    acc[0] += w * bflo(hv.x);
    acc[1] += w * bfhi(hv.x);
    acc[2] += w * bflo(hv.y);
    acc[3] += w * bfhi(hv.y);
  }
#pragma unroll
  for (int k = 0; k < 4; ++k) red4[rsub][c4 * 4 + k] = acc[k];
  __syncthreads();
  if (t < 256) {
    float v = red4[0][t] + red4[1][t] + red4[2][t] + red4[3][t];
    part[b * 256 + t] = v * invz;
  }
}

__global__ __launch_bounds__(256)
void pool_final_kernel(const float* __restrict__ part, float* __restrict__ out) {
  const int t = threadIdx.x;
  float acc = 0.f;
  for (int b = 0; b < 256; ++b) acc += part[b * 256 + t];
  out[t] = acc;
}

extern "C" void kernel_launch(void* const* d_in, const int* in_sizes, int n_in,
                              void* d_out, int out_size, void* d_ws, size_t ws_size,
                              hipStream_t stream) {
  const float* x      = (const float*)d_in[0];
  const int*   ei     = (const int*)d_in[1];
  const float* W1     = (const float*)d_in[2];
  const float* b1     = (const float*)d_in[3];
  const float* a_src1 = (const float*)d_in[4];
  const float* a_dst1 = (const float*)d_in[5];
  const float* W2     = (const float*)d_in[6];
  const float* b2     = (const float*)d_in[7];
  const float* a_src2 = (const float*)d_in[8];
  const float* a_dst2 = (const float*)d_in[9];
  const float* g1     = (const float*)d_in[10];
  const float* be1    = (const float*)d_in[11];
  const float* g2     = (const float*)d_in[12];
  const float* be2    = (const float*)d_in[13];
  const float* attn_w = (const float*)d_in[14];
  const float* attn_b = (const float*)d_in[15];
  float* out = (float*)d_out;

  char* p = (char*)d_ws;
  auto alloc = [&](size_t bytes) {
    char* r = p;
    p += (bytes + 255) & ~size_t(255);
    return r;
  };
  ushort* h   = (ushort*)alloc((size_t)N_NODES * 256 * 2);
  ushort* xb  = (ushort*)alloc((size_t)N_NODES * 256 * 2);
  ushort* xb1 = (ushort*)alloc((size_t)N_NODES * 256 * 2);
  ushort* hb2 = (ushort*)alloc((size_t)N_NODES * 256 * 2);
  float* as_  = (float*)alloc((size_t)N_NODES * 4 * 4);
  float* ad_  = (float*)alloc((size_t)N_NODES * 4 * 4);
  float* sbuf = (float*)alloc((size_t)N_NODES * 4);
  float* mz   = (float*)alloc(256);
  float* pm   = (float*)alloc((size_t)SPART * 4);
  float* pz   = (float*)alloc((size_t)SPART * 4);
  float* part = (float*)alloc((size_t)256 * 256 * 4);
  ushort* wt1 = (ushort*)alloc((size_t)256 * 256 * 2);
  ushort* wt2 = (ushort*)alloc((size_t)256 * 256 * 2);
  int* deg    = (int*)alloc((size_t)N_NODES * 4);
  int* rowp   = (int*)alloc((size_t)(N_NODES + 1) * 4);
  int* cur    = (int*)alloc((size_t)N_NODES * 4);
  int* colb   = (int*)alloc((size_t)TOT_E * 4);
  int* bsum   = (int*)alloc((size_t)SCAN_NB * 4);
  int* boff   = (int*)alloc((size_t)SCAN_NB * 4);

  const int EB = (TOT_E + 255) / 256;
  const int GB = N_NODES / 32;   // 625
  const int DB = N_NODES / 4;    // 5000
  const int XB = N_NODES * 256 / 8 / 256;  // 2500
  const int CONVB = 512 + XB + SCAN_NB;

  conv_inputs_kernel<<<CONVB, 256, 0, stream>>>(W1, W2, x, wt1, wt2, xb, deg);
  hist_kernel<<<EB, 256, 0, stream>>>(ei, deg);
  scan_blocks_kernel<<<SCAN_NB, 256, 0, stream>>>(deg, bsum);
  scan_tops_kernel<<<1, 128, 0, stream>>>(bsum, boff);
  scan_apply_kernel<<<SCAN_NB, 256, 0, stream>>>(deg, boff, rowp, cur);
  scatter_kernel<<<EB, 256, 0, stream>>>(ei, cur, colb);

  // layer 1
  gemm_alpha_kernel<<<GB, 256, 0, stream>>>(xb, wt1, a_src1, a_dst1, h, as_, ad_);
  attn_gather_ln_kernel<<<DB, 256, 0, stream>>>(h, as_, ad_, rowp, colb, b1, g1, be1,
                                                nullptr, xb1, nullptr, nullptr, nullptr);
  // layer 2
  gemm_alpha_kernel<<<GB, 256, 0, stream>>>(xb1, wt2, a_src2, a_dst2, h, as_, ad_);
  attn_gather_ln_kernel<<<DB, 256, 0, stream>>>(h, as_, ad_, rowp, colb, b2, g2, be2,
                                                xb1, hb2, attn_w, attn_b, sbuf);
  // pooling
  score_part_kernel<<<SPART, 256, 0, stream>>>(sbuf, pm, pz);
  score_comb_kernel<<<1, 64, 0, stream>>>(pm, pz, mz);
  pool_partial_kernel<<<256, 256, 0, stream>>>(hb2, sbuf, mz, part);
  pool_final_kernel<<<1, 256, 0, stream>>>(part, out);
}